// Round 1
// baseline (350.526 us; speedup 1.0000x reference)
//
#include <hip/hip_runtime.h>
#include <hip/hip_bf16.h>
#include <math.h>

// Problem constants: B=4, D=1024, N=2048, K=1024, fp32 in/out.
#define BB 4
#define DD 1024
#define NN 2048
#define KK 1024
#define NT128 16            // NN/128
#define NTRI 136            // 16*17/2 lower-triangular 128x128 tiles
#define TRI_ELEMS 16384     // 128*128

typedef __attribute__((ext_vector_type(4))) float f32x4;
typedef __attribute__((ext_vector_type(8))) short bfrag;

typedef __attribute__((address_space(1))) const unsigned int gu32;
typedef __attribute__((address_space(3))) unsigned int lu32;

// async global->LDS, 16B per lane; LDS dest = base + lane*16 (wave-uniform base)
__device__ __forceinline__ void async16(const void* g, void* l) {
  __builtin_amdgcn_global_load_lds((gu32*)g, (lu32*)l, 16, 0, 0);
}

__device__ __forceinline__ ushort f2b(float f) {  // fp32 -> bf16 RNE
  union { float f; unsigned u; } c; c.f = f;
  unsigned u = c.u + 0x7fffu + ((c.u >> 16) & 1u);
  return (ushort)(u >> 16);
}
__device__ __forceinline__ float b2f(ushort h) {
  union { unsigned u; float f; } c; c.u = ((unsigned)h) << 16;
  return c.f;
}

// ---------------------------------------------------------------------------
// prep: merged input transform, grid (64, 32, 6), block (32,8).
//  z<4 : x [b=z][d][n] fp32 -> x_hi (bf16 same layout), xT hi/lo ([b][n][d])
//  z>=4: weight w = (z-4)*2 + (bx>>5): W (K x D, [k][d]) -> WT [d][k] bf16
//        (WQ, WK split hi+lo; WV, WO hi only)
// ---------------------------------------------------------------------------
__global__ __launch_bounds__(256) void prep(
    const float* __restrict__ x,
    const float* __restrict__ WQ, const float* __restrict__ WK,
    const float* __restrict__ WV, const float* __restrict__ WO,
    ushort* __restrict__ xhi, ushort* __restrict__ xTh, ushort* __restrict__ xTl,
    ushort* __restrict__ qh, ushort* __restrict__ ql,
    ushort* __restrict__ kh, ushort* __restrict__ kl_,
    ushort* __restrict__ vh, ushort* __restrict__ oh) {
  const int z = blockIdx.z;
  const int tx = threadIdx.x, ty = threadIdx.y;
  __shared__ float tile[32][33];
  if (z < 4) {
    const int b = z;
    const int n0 = blockIdx.x * 32, d0 = blockIdx.y * 32;
    const float* xb = x + (long)b * DD * NN;
    ushort* xhb = xhi + (long)b * DD * NN;
#pragma unroll
    for (int r = 0; r < 4; ++r) {
      const int dl = ty + r * 8;
      const float v = xb[(long)(d0 + dl) * NN + n0 + tx];
      tile[dl][tx] = v;
      xhb[(long)(d0 + dl) * NN + n0 + tx] = f2b(v);
    }
    __syncthreads();
#pragma unroll
    for (int r = 0; r < 4; ++r) {
      const int nl = ty + r * 8;
      const float v = tile[tx][nl];
      const ushort h = f2b(v);
      const long o = (long)b * NN * DD + (long)(n0 + nl) * DD + d0 + tx;
      xTh[o] = h;
      xTl[o] = f2b(v - b2f(h));
    }
  } else {
    const int w = (z - 4) * 2 + (blockIdx.x >> 5);
    const float* W = (w == 0) ? WQ : (w == 1) ? WK : (w == 2) ? WV : WO;
    ushort* Th = (w == 0) ? qh : (w == 1) ? kh : (w == 2) ? vh : oh;
    ushort* Tl = (w == 0) ? ql : (w == 1) ? kl_ : nullptr;
    const int k0 = (blockIdx.x & 31) * 32, d0 = blockIdx.y * 32;
#pragma unroll
    for (int r = 0; r < 4; ++r) {
      const int kl = ty + r * 8;
      tile[kl][tx] = W[(long)(k0 + kl) * DD + d0 + tx];
    }
    __syncthreads();
#pragma unroll
    for (int r = 0; r < 4; ++r) {
      const int dl = ty + r * 8;
      const float v = tile[tx][dl];              // = W[k0+tx][d0+dl]
      const ushort h = f2b(v);
      const long o = (long)(d0 + dl) * KK + k0 + tx;
      Th[o] = h;
      if (Tl) Tl[o] = f2b(v - b2f(h));
    }
  }
}

// ---------------------------------------------------------------------------
// Merged weight-product GEMM, 64x64 tiles, BK=32, 512 blocks:
//   id<256 : Mqk[m,n] = sum_k wqT[m,k] wkT[n,k]  (split 3-MFMA, split store)
//   id>=256: Mov[m,n] = sum_k woT[m,k] wvT[n,k]  (plain bf16)
// LDS rows are 32 bf16 (64B): rows alias every 2 -> XOR swizzle by (row>>1)&3.
// ---------------------------------------------------------------------------
__global__ __launch_bounds__(256) void gemm_w(
    const ushort* __restrict__ qh, const ushort* __restrict__ ql,
    const ushort* __restrict__ kh, const ushort* __restrict__ kl_,
    const ushort* __restrict__ vh, const ushort* __restrict__ oh,
    ushort* __restrict__ mqk_h, ushort* __restrict__ mqk_l,
    ushort* __restrict__ mov_h) {
  extern __shared__ ushort smem[];
  ushort* sAh = smem;            // [64][32] 4KB
  ushort* sAl = smem + 2048;
  ushort* sBh = smem + 4096;
  ushort* sBl = smem + 6144;

  const int id = blockIdx.x;
  const int half = id >> 8;                  // 0 = Mqk (split), 1 = Mov (plain)
  const int t = id & 255;
  const int m0 = (t >> 4) * 64, n0 = (t & 15) * 64;
  const ushort* A_h = half ? oh : qh;
  const ushort* B_h = half ? vh : kh;

  const int tid = threadIdx.x;
  const int lane = tid & 63, wave = tid >> 6;
  const int wm = (wave & 1) * 32, wn = (wave >> 1) * 32;
  const int r16 = lane & 15, quad = lane >> 4;
  const int kc = ((lane & 3) ^ ((lane >> 3) & 3)) * 8;   // swizzled k-chunk
  const int srow = lane >> 2;

  f32x4 acc[2][2];
#pragma unroll
  for (int i = 0; i < 2; ++i)
#pragma unroll
    for (int j = 0; j < 2; ++j) acc[i][j] = (f32x4){0.f, 0.f, 0.f, 0.f};

  for (int k0 = 0; k0 < KK; k0 += 32) {
    __syncthreads();
    {
      const int row = wave * 16 + srow;
      const long aoff = (long)(m0 + row) * KK + k0 + kc;
      const long boff = (long)(n0 + row) * KK + k0 + kc;
      async16(A_h + aoff, sAh + wave * 512);
      async16(B_h + boff, sBh + wave * 512);
      if (half == 0) {
        async16(ql + aoff, sAl + wave * 512);
        async16(kl_ + boff, sBl + wave * 512);
      }
    }
    __syncthreads();

    const int sw = (r16 >> 1) & 3;
    bfrag ah[2], bh[2], al[2], bl[2];
#pragma unroll
    for (int t2 = 0; t2 < 2; ++t2) {
      ah[t2] = *(const bfrag*)&sAh[(wm + t2 * 16 + r16) * 32 + (quad ^ sw) * 8];
      bh[t2] = *(const bfrag*)&sBh[(wn + t2 * 16 + r16) * 32 + (quad ^ sw) * 8];
      if (half == 0) {
        al[t2] = *(const bfrag*)&sAl[(wm + t2 * 16 + r16) * 32 + (quad ^ sw) * 8];
        bl[t2] = *(const bfrag*)&sBl[(wn + t2 * 16 + r16) * 32 + (quad ^ sw) * 8];
      }
    }
#pragma unroll
    for (int mt = 0; mt < 2; ++mt)
#pragma unroll
      for (int nt = 0; nt < 2; ++nt) {
        acc[mt][nt] = __builtin_amdgcn_mfma_f32_16x16x32_bf16(ah[mt], bh[nt], acc[mt][nt], 0, 0, 0);
        if (half == 0) {
          acc[mt][nt] = __builtin_amdgcn_mfma_f32_16x16x32_bf16(ah[mt], bl[nt], acc[mt][nt], 0, 0, 0);
          acc[mt][nt] = __builtin_amdgcn_mfma_f32_16x16x32_bf16(al[mt], bh[nt], acc[mt][nt], 0, 0, 0);
        }
      }
  }

#pragma unroll
  for (int mt = 0; mt < 2; ++mt)
#pragma unroll
    for (int nt = 0; nt < 2; ++nt)
#pragma unroll
      for (int reg = 0; reg < 4; ++reg) {
        const int ml = wm + mt * 16 + quad * 4 + reg;
        const int nl = wn + nt * 16 + r16;
        const float v = acc[mt][nt][reg];
        const long o = (long)(m0 + ml) * DD + n0 + nl;
        if (half == 0) {
          const ushort h = f2b(v);
          mqk_h[o] = h;
          mqk_l[o] = f2b(v - b2f(h));
        } else {
          mov_h[o] = f2b(v);
        }
      }
}

// ---------------------------------------------------------------------------
// bf16 MFMA GEMM, 128x128 block tile, 4 waves (2x2) of 64x64, BK=32,
// 16x16x32 MFMA, depth-2 software pipeline with COUNTED vmcnt:
//   - LDS double buffer (2 x 32KB split / 2 x 16KB plain) -> same LDS total
//     as the old single-buffered BK=64 version, so still 2 blocks/CU.
//   - Raw s_barrier + asm s_waitcnt vmcnt(LPI): the prefetch for K-step t+2
//     stays in flight across the barriers and has a full K-step of MFMA to
//     hide under; vmcnt never drains to 0 in the main loop (T4 mechanism).
//     (__syncthreads would force the compiler's vmcnt(0) drain = old 30%
//     MfmaUtil ceiling.)
//   - Overwrite safety: frag ds_reads of buf[t&1] are drained (lgkmcnt(0))
//     and barriered before STAGE(t+2) re-targets buf[t&1]. All barrier
//     conditions are block-uniform.
// Bank swizzle (BK=32: rows are 64B = 4 chunks of 8 bf16): physical chunk =
// logical ^ f(row), f(row) = ((row>>2)&1) | (row&2). Per aligned 8-lane group
// of a ds_read_b128 the 8 16B slots land on 8 distinct bank quads ->
// conflict-free. Staging realizes it by pre-swizzling the per-lane global
// source (global_load_lds LDS dest stays linear).
// Fragment layouts (HW-verified, learn_hip m89):
//   A[m=lane&15][k=quad*8+j], B[n=lane&15][k=quad*8+j],
//   C/D: col=lane&15, row=quad*4+reg.
// SPLIT: hi+lo bf16 operands, 3 MFMAs (hh, hl, lh) ~= fp32 accuracy.
// TRIA : A staged from triangular tile layout; K limited to m0+128.
// SWIZ : XCD-locality block mapping (assumes xcd = blockIdx.x % 8):
//   1: 1-D grid 512, g=(blk&7)*64+(blk>>3); P=g>>3 -> (b=P>>4, m0=(P&15)*128),
//      n0=(g&7)*128.                                  [M=16 tiles, N=8 tiles]
//   2: 1-D grid 544 (logits tri), g=(blk&7)*68+(blk>>3); b=g/136, t=g%136.
//   3: 1-D grid 512, causal-balanced: XCD x owns mtiles {x, 15-x} (constant
//      work), idx=blk>>3: q=idx>>3 -> b=q>>1, m=(q&1)?15-x:x; n0=(idx&7)*128.
//   4: 1-D grid 512, swapped roles: P=g>>3 -> (b=P>>4, n0=(P&15)*128),
//      m0=(g&7)*128.                                  [M=8 tiles, N=16 tiles]
// STORE 0: split bf16 (C0=hi, C1=lo), row-major ldc
//       1: triangular-tile fp32
//       2: bf16 row-major
//       3: fp32 row-major with residual add from Res
// ---------------------------------------------------------------------------
template <int SPLIT, int TRIA, int STORE, int SWIZ>
__global__ __launch_bounds__(256) void gemm_mfma(
    const ushort* __restrict__ Ah, const ushort* __restrict__ Al,
    const ushort* __restrict__ Bh, const ushort* __restrict__ Bl,
    void* __restrict__ C0, void* __restrict__ C1, const float* __restrict__ Res,
    int K, int lda, int ldb, int ldc,
    long bA, long bB, long bC, long bR) {
  extern __shared__ ushort smem[];
  constexpr int DBS = SPLIT ? 16384 : 8192;   // ushorts per pipeline buffer
  constexpr int BO  = SPLIT ? 8192  : 4096;   // B-hi offset within buffer
  // array offsets within buffer: Ah@0 [, Al@4096], Bh@BO [, Bl@12288]

  int b, m0, n0, tiC = 0;
  if (SWIZ == 2) {
    const int g = (blockIdx.x & 7) * 68 + (blockIdx.x >> 3);
    b = g / NTRI;
    int t = g - b * NTRI;
    int ti = 0;
    while ((ti + 1) * (ti + 2) / 2 <= t) ++ti;
    const int tj = t - ti * (ti + 1) / 2;
    m0 = ti * 128; n0 = tj * 128; tiC = t;
  } else if (SWIZ == 1) {
    const int g = (blockIdx.x & 7) * 64 + (blockIdx.x >> 3);
    const int P = g >> 3;
    b = P >> 4;
    m0 = (P & 15) * 128;
    n0 = (g & 7) * 128;
  } else if (SWIZ == 3) {
    const int xcd = blockIdx.x & 7;
    const int idx = blockIdx.x >> 3;      // [0,64)
    const int q = idx >> 3;               // [0,8)
    b = q >> 1;
    const int mt_ = (q & 1) ? (15 - xcd) : xcd;
    m0 = mt_ * 128;
    n0 = (idx & 7) * 128;
  } else {  // SWIZ == 4
    const int g = (blockIdx.x & 7) * 64 + (blockIdx.x >> 3);
    const int P = g >> 3;
    b = P >> 4;
    n0 = (P & 15) * 128;
    m0 = (g & 7) * 128;
  }
  const int kmax = TRIA ? (m0 + 128) : K;
  int triA0 = 0;
  if (TRIA) { const int ti = m0 >> 7; triA0 = ti * (ti + 1) / 2; }

  const ushort* A_h = Ah + (long)b * bA;
  const ushort* B_h = Bh + (long)b * bB;
  const ushort* A_l = SPLIT ? Al + (long)b * bA : nullptr;
  const ushort* B_l = SPLIT ? Bl + (long)b * bB : nullptr;

  const int tid = threadIdx.x;
  const int lane = tid & 63, wave = tid >> 6;
  const int wm = (wave & 1) * 64, wn = (wave >> 1) * 64;
  const int r16 = lane & 15, quad = lane >> 4;

  // staging constants: each wave stages 32 rows/array per K-step via 2
  // async16 of 16 rows each; lane covers row (lane>>2), phys chunk (lane&3).
  const int srow = lane >> 2;                                  // [0,16)
  const int fsw = ((lane >> 4) & 1) | (srow & 2);              // = f(row)
  const int kc = ((lane & 3) ^ fsw) * 8;                       // global k-chunk

  f32x4 acc[4][4];
#pragma unroll
  for (int i = 0; i < 4; ++i)
#pragma unroll
    for (int j = 0; j < 4; ++j) acc[i][j] = (f32x4){0.f, 0.f, 0.f, 0.f};

  const int T = kmax >> 5;   // K-steps of 32 (>= 4 in all uses)

  auto STAGE = [&](int db, int t) {
    const int k0 = t << 5;
    ushort* dst = smem + db * DBS;
#pragma unroll
    for (int h = 0; h < 2; ++h) {
      const int row = wave * 32 + h * 16 + srow;
      long aoff;
      if (TRIA)
        aoff = (long)(triA0 + (k0 >> 7)) * TRI_ELEMS + (long)row * 128 + (k0 & 127) + kc;
      else
        aoff = (long)(m0 + row) * lda + k0 + kc;
      const long boff = (long)(n0 + row) * ldb + k0 + kc;
      const int d0 = wave * 1024 + h * 512;
      async16(A_h + aoff, dst + d0);
      async16(B_h + boff, dst + BO + d0);
      if (SPLIT) {
        async16(A_l + aoff, dst + 4096 + d0);
        async16(B_l + boff, dst + 12288 + d0);
      }
    }
  };

  // prologue: tiles 0 and 1 in flight (2*LPI outstanding per wave)
  STAGE(0, 0);
  STAGE(1, 1);

  const int fr = ((r16 >> 2) & 1) | (r16 & 2);
  const int pc8 = (quad ^ fr) * 8;             // physical chunk for frag reads

  for (int t = 0; t < T; ++t) {
    const int db = t & 1;
    if (t + 1 < T) {
      // allow the LPI loads of tile t+1 (and any for t+2) to stay in flight;
      // wait only for tile t's loads. LPI = 8 (split) / 4 (plain) per wave.
      if (SPLIT) asm volatile("s_waitcnt vmcnt(8)" ::: "memory");
      else       asm volatile("s_waitcnt vmcnt(4)" ::: "memory");
    } else {
      asm volatile("s_waitcnt vmcnt(0)" ::: "memory");
    }
    __builtin_amdgcn_s_barrier();              // buf[db] ready for all waves

    const ushort* src = smem + db * DBS;
    bfrag ah[4], bh[4], al[4], bl[4];
#pragma unroll
    for (int t4 = 0; t4 < 4; ++t4) {
      ah[t4] = *(const bfrag*)&src[(wm + t4 * 16 + r16) * 32 + pc8];
      bh[t4] = *(const bfrag*)&src[BO + (wn + t4 * 16 + r16) * 32 + pc8];
      if (SPLIT) {
        al[t4] = *(const bfrag*)&src[4096 + (wm + t4 * 16 + r16) * 32 + pc8];
        bl[t4] = *(const bfrag*)&src[12288 + (wn + t4 * 16 + r16) * 32 + pc8];
      }
    }
    if (t + 2 < T) {
      // all waves' ds_reads of buf[db] must land before re-targeting it
      asm volatile("s_waitcnt lgkmcnt(0)" ::: "memory");
      __builtin_amdgcn_s_barrier();
      STAGE(db, t + 2);                        // issued before MFMA cluster
    }
#pragma unroll
    for (int mt = 0; mt < 4; ++mt)
#pragma unroll
      for (int nt = 0; nt < 4; ++nt) {
        acc[mt][nt] = __builtin_amdgcn_mfma_f32_16x16x32_bf16(ah[mt], bh[nt], acc[mt][nt], 0, 0, 0);
        if (SPLIT) {
          acc[mt][nt] = __builtin_amdgcn_mfma_f32_16x16x32_bf16(ah[mt], bl[nt], acc[mt][nt], 0, 0, 0);
          acc[mt][nt] = __builtin_amdgcn_mfma_f32_16x16x32_bf16(al[mt], bh[nt], acc[mt][nt], 0, 0, 0);
        }
      }
  }

  // epilogue
#pragma unroll
  for (int mt = 0; mt < 4; ++mt)
#pragma unroll
    for (int nt = 0; nt < 4; ++nt)
#pragma unroll
      for (int reg = 0; reg < 4; ++reg) {
        const int ml = wm + mt * 16 + quad * 4 + reg;
        const int nl = wn + nt * 16 + r16;
        const float v = acc[mt][nt][reg];
        if (STORE == 0) {
          ushort* Ch = (ushort*)C0 + (long)b * bC;
          ushort* Cl = (ushort*)C1 + (long)b * bC;
          const long o = (long)(m0 + ml) * ldc + n0 + nl;
          const ushort h = f2b(v);
          Ch[o] = h;
          Cl[o] = f2b(v - b2f(h));
        } else if (STORE == 1) {
          float* C = (float*)C0 + (long)b * bC + (long)tiC * TRI_ELEMS;
          C[ml * 128 + nl] = v;
        } else if (STORE == 2) {
          ushort* C = (ushort*)C0 + (long)b * bC;
          C[(long)(m0 + ml) * ldc + n0 + nl] = f2b(v);
        } else {
          float* C = (float*)C0 + (long)b * bC;
          const float* R = Res + (long)b * bR;
          const long o = (long)(m0 + ml) * ldc + n0 + nl;
          C[o] = R[o] + v;
        }
      }
}

// ---------------------------------------------------------------------------
// Causal softmax over triangular-tiled logits. One block per row (b, i).
// Writes bf16 A in tri layout, zero-filling diagonal-tile cols beyond i.
// ---------------------------------------------------------------------------
__global__ __launch_bounds__(256) void softmax_tri(
    const float* __restrict__ L, ushort* __restrict__ Aout) {
  const int row = blockIdx.x;
  const int b = row >> 11, i = row & (NN - 1);
  const int ti = i >> 7, ml = i & 127;
  const long base = (long)b * ((long)NTRI * TRI_ELEMS);
  const int trib = ti * (ti + 1) / 2;
  const int len = i + 1;
  const int tot = (ti + 1) * 128;
  const int tid = threadIdx.x;
  __shared__ float red[256];
  float vv[8];
  float m = -INFINITY;
#pragma unroll
  for (int u = 0; u < 8; ++u) {
    const int j = tid + u * 256;
    if (j < len) {
      const float v = L[base + (long)(trib + (j >> 7)) * TRI_ELEMS + ml * 128 + (j & 127)];
      vv[u] = v;
      m = fmaxf(m, v);
    }
  }
  red[tid] = m; __syncthreads();
  for (int s = 128; s; s >>= 1) { if (tid < s) red[tid] = fmaxf(red[tid], red[tid + s]); __syncthreads(); }
  m = red[0]; __syncthreads();
  float sum = 0.f;
#pragma unroll
  for (int u = 0; u < 8; ++u) {
    const int j = tid + u * 256;
    if (j < len) { const float e = __expf(vv[u] - m); vv[u] = e; sum += e; }
  }
  red[tid] = sum; __syncthreads();
  for (int s = 128; s; s >>= 1) { if (tid < s) red[tid] += red[tid + s]; __syncthreads(); }
  const float inv = 1.f / red[0];
#pragma unroll
  for (int u = 0; u < 8; ++u) {
    const int j = tid + u * 256;
    if (j < tot) {
      const ushort o = (j < len) ? f2b(vv[u] * inv) : (ushort)0;
      Aout[base + (long)(trib + (j >> 7)) * TRI_ELEMS + ml * 128 + (j & 127)] = o;
    }
  }
}

// ---------------------------------------------------------------------------
// Pipeline (all MFMA operands k-contiguous by construction):
//  0. prep: x -> x_hi, xT hi/lo; W_Q..W_O -> WT [d][k] bf16     (1 dispatch)
//  1. gemm_w: Mqk (split) + Mov (plain) in one 512-block dispatch
//  2. tT[i,d] = sum_e xT[i,e] Mqk[d,e]      split MFMA, split store, SWIZ=1
//  3. logits[i,j] = sum_d xT[i,d] tT[j,d]   split MFMA, tri tiles, SWIZ=2
//  4. A = causal softmax (bf16, tri layout, zero-padded diag tiles)
//  5. ctxT[i,e] = sum_{t<=i} A[i,t] x[e,t]  bf16 MFMA, causal K, SWIZ=3 (bal)
//  6. out[d,i] = x[d,i] + sum_e Mov[d,e] ctxT[i,e]   bf16 MFMA + res, SWIZ=4
// ---------------------------------------------------------------------------
extern "C" void kernel_launch(void* const* d_in, const int* in_sizes, int n_in,
                              void* d_out, int out_size, void* d_ws, size_t ws_size,
                              hipStream_t stream) {
  const float* x = (const float*)d_in[0];
  const float* WQ = (const float*)d_in[1];
  const float* WK = (const float*)d_in[2];
  const float* WV = (const float*)d_in[3];
  const float* WO = (const float*)d_in[4];
  float* out = (float*)d_out;

  const long XE = (long)BB * DD * NN;    // 8M elements
  const long WE = (long)DD * KK;         // 1M elements
  ushort* x_hi = (ushort*)d_ws;
  ushort* xTh = x_hi + XE;
  ushort* xTl = xTh + XE;
  ushort* wqT_h = xTl + XE;
  ushort* wqT_l = wqT_h + WE;
  ushort* wkT_h = wqT_l + WE;
  ushort* wkT_l = wkT_h + WE;
  ushort* wvT_h = wkT_l + WE;
  ushort* woT_h = wvT_h + WE;
  ushort* mqk_h = woT_h + WE;
  ushort* mqk_l = mqk_h + WE;
  ushort* mov_h = mqk_l + WE;
  ushort* tTh = mov_h + WE;
  ushort* tTl = tTh + XE;
  float* logits = (float*)(tTl + XE);    // B*NTRI*TRI_ELEMS fp32 (~35.7MB)
  ushort* A_tri = tTh;                   // overlays tT hi+lo (dead after step 3)
  ushort* ctxT = (ushort*)logits;        // overlays logits (dead after softmax)
  const long TRIB = (long)NTRI * TRI_ELEMS;
  const long XB = XE / BB;

  prep<<<dim3(64, 32, 6), dim3(32, 8), 0, stream>>>(
      x, WQ, WK, WV, WO, x_hi, xTh, xTl,
      wqT_h, wqT_l, wkT_h, wkT_l, wvT_h, woT_h);

  // Mqk (split) + Mov (plain), merged 64-tile dispatch
  gemm_w<<<dim3(512), 256, 16384, stream>>>(
      wqT_h, wqT_l, wkT_h, wkT_l, wvT_h, woT_h, mqk_h, mqk_l, mov_h);

  // tT = xT * Mqk^T (split, XCD-swizzled, BK=32 dbuf, 64KB LDS)
  gemm_mfma<1, 0, 0, 1><<<dim3(512), 256, 65536, stream>>>(
      xTh, xTl, mqk_h, mqk_l, tTh, tTl, nullptr,
      DD, DD, DD, DD, XB, 0, XB, 0);

  // logits (lower tri tiles, XCD-swizzled, BK=32 dbuf, 64KB LDS)
  gemm_mfma<1, 0, 1, 2><<<dim3(BB * NTRI), 256, 65536, stream>>>(
      xTh, xTl, tTh, tTl, logits, nullptr, nullptr,
      DD, DD, DD, 0, XB, XB, TRIB, 0);

  softmax_tri<<<dim3(BB * NN), 256, 0, stream>>>(logits, A_tri);

  // ctxT = A * x^T (tri A, causal K-limit, balanced XCD swizzle)
  gemm_mfma<0, 1, 2, 3><<<dim3(512), 256, 32768, stream>>>(
      A_tri, nullptr, x_hi, nullptr, ctxT, nullptr, nullptr,
      NN, 0, NN, DD, TRIB, XB, XB, 0);

  // out = x + Mov * ctx (SWIZ=4: M=8 d-tiles, N=16 i-tiles)
  gemm_mfma<0, 0, 3, 4><<<dim3(512), 256, 32768, stream>>>(
      mov_h, nullptr, ctxT, nullptr, out, nullptr, x,
      DD, DD, DD, NN, 0, XB, XB, XB);
}

// Round 2
// 349.941 us; speedup vs baseline: 1.0017x; 1.0017x over previous
//
#include <hip/hip_runtime.h>
#include <hip/hip_bf16.h>
#include <math.h>

// Problem constants: B=4, D=1024, N=2048, K=1024, fp32 in/out.
#define BB 4
#define DD 1024
#define NN 2048
#define KK 1024
#define NT128 16            // NN/128
#define NTRI 136            // 16*17/2 lower-triangular 128x128 tiles
#define TRI_ELEMS 16384     // 128*128

typedef __attribute__((ext_vector_type(4))) float f32x4;
typedef __attribute__((ext_vector_type(8))) short bfrag;

typedef __attribute__((address_space(1))) const unsigned int gu32;
typedef __attribute__((address_space(3))) unsigned int lu32;

// async global->LDS, 16B per lane; LDS dest = base + lane*16 (wave-uniform base)
__device__ __forceinline__ void async16(const void* g, void* l) {
  __builtin_amdgcn_global_load_lds((gu32*)g, (lu32*)l, 16, 0, 0);
}

__device__ __forceinline__ ushort f2b(float f) {  // fp32 -> bf16 RNE
  union { float f; unsigned u; } c; c.f = f;
  unsigned u = c.u + 0x7fffu + ((c.u >> 16) & 1u);
  return (ushort)(u >> 16);
}
__device__ __forceinline__ float b2f(ushort h) {
  union { unsigned u; float f; } c; c.u = ((unsigned)h) << 16;
  return c.f;
}

// ---------------------------------------------------------------------------
// prep: merged input transform, grid (64, 32, 6), block (32,8).
//  z<4 : x [b=z][d][n] fp32 -> x_hi (bf16 same layout), xT hi/lo ([b][n][d])
//  z>=4: weight w = (z-4)*2 + (bx>>5): W (K x D, [k][d]) -> WT [d][k] bf16
//        (WQ, WK split hi+lo; WV, WO hi only)
// ---------------------------------------------------------------------------
__global__ __launch_bounds__(256) void prep(
    const float* __restrict__ x,
    const float* __restrict__ WQ, const float* __restrict__ WK,
    const float* __restrict__ WV, const float* __restrict__ WO,
    ushort* __restrict__ xhi, ushort* __restrict__ xTh, ushort* __restrict__ xTl,
    ushort* __restrict__ qh, ushort* __restrict__ ql,
    ushort* __restrict__ kh, ushort* __restrict__ kl_,
    ushort* __restrict__ vh, ushort* __restrict__ oh) {
  const int z = blockIdx.z;
  const int tx = threadIdx.x, ty = threadIdx.y;
  __shared__ float tile[32][33];
  if (z < 4) {
    const int b = z;
    const int n0 = blockIdx.x * 32, d0 = blockIdx.y * 32;
    const float* xb = x + (long)b * DD * NN;
    ushort* xhb = xhi + (long)b * DD * NN;
#pragma unroll
    for (int r = 0; r < 4; ++r) {
      const int dl = ty + r * 8;
      const float v = xb[(long)(d0 + dl) * NN + n0 + tx];
      tile[dl][tx] = v;
      xhb[(long)(d0 + dl) * NN + n0 + tx] = f2b(v);
    }
    __syncthreads();
#pragma unroll
    for (int r = 0; r < 4; ++r) {
      const int nl = ty + r * 8;
      const float v = tile[tx][nl];
      const ushort h = f2b(v);
      const long o = (long)b * NN * DD + (long)(n0 + nl) * DD + d0 + tx;
      xTh[o] = h;
      xTl[o] = f2b(v - b2f(h));
    }
  } else {
    const int w = (z - 4) * 2 + (blockIdx.x >> 5);
    const float* W = (w == 0) ? WQ : (w == 1) ? WK : (w == 2) ? WV : WO;
    ushort* Th = (w == 0) ? qh : (w == 1) ? kh : (w == 2) ? vh : oh;
    ushort* Tl = (w == 0) ? ql : (w == 1) ? kl_ : nullptr;
    const int k0 = (blockIdx.x & 31) * 32, d0 = blockIdx.y * 32;
#pragma unroll
    for (int r = 0; r < 4; ++r) {
      const int kl = ty + r * 8;
      tile[kl][tx] = W[(long)(k0 + kl) * DD + d0 + tx];
    }
    __syncthreads();
#pragma unroll
    for (int r = 0; r < 4; ++r) {
      const int dl = ty + r * 8;
      const float v = tile[tx][dl];              // = W[k0+tx][d0+dl]
      const ushort h = f2b(v);
      const long o = (long)(d0 + dl) * KK + k0 + tx;
      Th[o] = h;
      if (Tl) Tl[o] = f2b(v - b2f(h));
    }
  }
}

// ---------------------------------------------------------------------------
// Merged weight-product GEMM, 64x64 tiles, BK=32, 512 blocks:
//   id<256 : Mqk[m,n] = sum_k wqT[m,k] wkT[n,k]  (split 3-MFMA, split store)
//   id>=256: Mov[m,n] = sum_k woT[m,k] wvT[n,k]  (plain bf16)
// ---------------------------------------------------------------------------
__global__ __launch_bounds__(256) void gemm_w(
    const ushort* __restrict__ qh, const ushort* __restrict__ ql,
    const ushort* __restrict__ kh, const ushort* __restrict__ kl_,
    const ushort* __restrict__ vh, const ushort* __restrict__ oh,
    ushort* __restrict__ mqk_h, ushort* __restrict__ mqk_l,
    ushort* __restrict__ mov_h) {
  extern __shared__ ushort smem[];
  ushort* sAh = smem;            // [64][32] 4KB
  ushort* sAl = smem + 2048;
  ushort* sBh = smem + 4096;
  ushort* sBl = smem + 6144;

  const int id = blockIdx.x;
  const int half = id >> 8;                  // 0 = Mqk (split), 1 = Mov (plain)
  const int t = id & 255;
  const int m0 = (t >> 4) * 64, n0 = (t & 15) * 64;
  const ushort* A_h = half ? oh : qh;
  const ushort* B_h = half ? vh : kh;

  const int tid = threadIdx.x;
  const int lane = tid & 63, wave = tid >> 6;
  const int wm = (wave & 1) * 32, wn = (wave >> 1) * 32;
  const int r16 = lane & 15, quad = lane >> 4;
  const int kc = ((lane & 3) ^ ((lane >> 3) & 3)) * 8;   // swizzled k-chunk
  const int srow = lane >> 2;

  f32x4 acc[2][2];
#pragma unroll
  for (int i = 0; i < 2; ++i)
#pragma unroll
    for (int j = 0; j < 2; ++j) acc[i][j] = (f32x4){0.f, 0.f, 0.f, 0.f};

  for (int k0 = 0; k0 < KK; k0 += 32) {
    __syncthreads();
    {
      const int row = wave * 16 + srow;
      const long aoff = (long)(m0 + row) * KK + k0 + kc;
      const long boff = (long)(n0 + row) * KK + k0 + kc;
      async16(A_h + aoff, sAh + wave * 512);
      async16(B_h + boff, sBh + wave * 512);
      if (half == 0) {
        async16(ql + aoff, sAl + wave * 512);
        async16(kl_ + boff, sBl + wave * 512);
      }
    }
    __syncthreads();

    const int sw = (r16 >> 1) & 3;
    bfrag ah[2], bh[2], al[2], bl[2];
#pragma unroll
    for (int t2 = 0; t2 < 2; ++t2) {
      ah[t2] = *(const bfrag*)&sAh[(wm + t2 * 16 + r16) * 32 + (quad ^ sw) * 8];
      bh[t2] = *(const bfrag*)&sBh[(wn + t2 * 16 + r16) * 32 + (quad ^ sw) * 8];
      if (half == 0) {
        al[t2] = *(const bfrag*)&sAl[(wm + t2 * 16 + r16) * 32 + (quad ^ sw) * 8];
        bl[t2] = *(const bfrag*)&sBl[(wn + t2 * 16 + r16) * 32 + (quad ^ sw) * 8];
      }
    }
#pragma unroll
    for (int mt = 0; mt < 2; ++mt)
#pragma unroll
      for (int nt = 0; nt < 2; ++nt) {
        acc[mt][nt] = __builtin_amdgcn_mfma_f32_16x16x32_bf16(ah[mt], bh[nt], acc[mt][nt], 0, 0, 0);
        if (half == 0) {
          acc[mt][nt] = __builtin_amdgcn_mfma_f32_16x16x32_bf16(ah[mt], bl[nt], acc[mt][nt], 0, 0, 0);
          acc[mt][nt] = __builtin_amdgcn_mfma_f32_16x16x32_bf16(al[mt], bh[nt], acc[mt][nt], 0, 0, 0);
        }
      }
  }

#pragma unroll
  for (int mt = 0; mt < 2; ++mt)
#pragma unroll
    for (int nt = 0; nt < 2; ++nt)
#pragma unroll
      for (int reg = 0; reg < 4; ++reg) {
        const int ml = wm + mt * 16 + quad * 4 + reg;
        const int nl = wn + nt * 16 + r16;
        const float v = acc[mt][nt][reg];
        const long o = (long)(m0 + ml) * DD + n0 + nl;
        if (half == 0) {
          const ushort h = f2b(v);
          mqk_h[o] = h;
          mqk_l[o] = f2b(v - b2f(h));
        } else {
          mov_h[o] = f2b(v);
        }
      }
}

// ---------------------------------------------------------------------------
// gemm_split8: the two big split GEMMs, phased schedule (T3+T4 structure +
// T5 setprio, m201-style regime).
//   Tile 256x128, BK=32, 8 waves (512 thr) as 4m x 2n -> per-wave 64x64
//   (acc[4][4]); halves ds_read:MFMA instruction ratio vs the old 64x32.
//   LDS: static 96KB = 2 buffers x (A[256][64] 32KB + B[128][64] 16KB).
//   hi|lo PACKED per row: 128B row = 8 chunks of 16B; chunks 0-3 = hi
//   k-chunks, 4-7 = lo. So rows are 128B and the round-0-proven bank
//   swizzle applies: physical chunk = logical ^ (row&7)  (0 conflicts).
//   Staging realizes the swizzle by pre-swizzling the per-lane GLOBAL source
//   (global_load_lds LDS dest must stay linear, m104/m173).
// Schedule per K-tile t (db=t&1), 2 barriers/tile (m201's per-K rate):
//   vmcnt(0)        ; tile t's 6 loads (issued a full tile ago -> ~free wait)
//   s_barrier       ; buf[db] ready for all waves; also fences t-1 reads
//   STAGE(t+1 -> buf[db^1])   ; 6 async16, in flight across the next tile
//   16 ds_reads of buf[db]    ; compiler schedules counted lgkmcnt
//   setprio(1); 24 MFMA (mt 0-1 x nt 0-3 x3); setprio(0)
//   s_barrier       ; phase-lock (role-split for setprio)
//   setprio(1); 24 MFMA (mt 2-3); setprio(0)
// Safety: STAGE(t+1->db^1) is after barrier#1, which all waves reach only
// after their tile-(t-1) reads of db^1 returned (MFMA data dep) -> no race.
// MODE 0: step 2 (tT = xT x Mqk^T), grid 256, split hi/lo bf16 store.
// MODE 1: step 3 (logits, lower-tri), grid 288, fp32 tri-tile store; block
//   covers 2 tri-rows (ti=2I, 2I+1); cols beyond diag (tj>ti) discarded.
// ---------------------------------------------------------------------------
template <int MODE>
__global__ __launch_bounds__(512, 2) void gemm_split8(
    const ushort* __restrict__ Ah, const ushort* __restrict__ Al,
    const ushort* __restrict__ Bh, const ushort* __restrict__ Bl,
    void* __restrict__ C0, void* __restrict__ C1,
    int lda, int ldb, int ldc, long bA, long bB, long bC) {
  __shared__ ushort smem[49152];               // 2 x 24576 elems = 96KB

  int b, m0, n0, tj = 0;
  if (MODE == 0) {
    // 256 blocks: g = xcd-chunked; I in [0,32) -> (b, m0), n0 = 8 j-tiles
    const int g = (blockIdx.x & 7) * 32 + (blockIdx.x >> 3);
    const int I = g >> 3;
    b = I >> 3;
    m0 = (I & 7) * 256;
    n0 = (g & 7) * 128;
  } else {
    // 288 blocks: per batch 72 = sum_{I<8}(2I+2) blocks, jt <= 2I+1
    const int g = (blockIdx.x & 7) * 36 + (blockIdx.x >> 3);
    b = g / 72;
    const int r = g - b * 72;
    int I = 0;
    while ((I + 1) * (I + 2) <= r) ++I;        // prefix(I) = I*(I+1)
    const int jt = r - I * (I + 1);
    m0 = I * 256;
    n0 = jt * 128;
    tj = jt;
  }

  const ushort* A_h = Ah + (long)b * bA;
  const ushort* A_l = Al + (long)b * bA;
  const ushort* B_h = Bh + (long)b * bB;
  const ushort* B_l = Bl + (long)b * bB;

  const int tid = threadIdx.x;
  const int lane = tid & 63, wave = tid >> 6;  // wave in [0,8)
  const int wm = (wave & 3) * 64, wn = (wave >> 2) * 64;
  const int r16 = lane & 15, quad = lane >> 4;
  const int rk = r16 & 7;                      // row&7 for frag reads

  // staging lane mapping: 8 rows x 8 phys chunks per async16 (1KB)
  const int lrow = lane >> 3;                  // row within 8-row segment
  const int lc = (lane & 7) ^ lrow;            // logical chunk = phys ^ row&7
  const int lck = (lc & 3) * 8;                // k-offset of the chunk
  const bool lo_src = lc >= 4;                 // chunks 4-7 come from *_l

  f32x4 acc[4][4];
#pragma unroll
  for (int i = 0; i < 4; ++i)
#pragma unroll
    for (int j = 0; j < 4; ++j) acc[i][j] = (f32x4){0.f, 0.f, 0.f, 0.f};

  auto STAGE = [&](int db, int t) {
    const int k0 = t << 5;
    ushort* dst = smem + db * 24576;
#pragma unroll
    for (int s = 0; s < 4; ++s) {              // A: 32 segs / 8 waves
      const int seg = wave * 4 + s;            // [0,32)
      const int row = seg * 8 + lrow;          // [0,256)
      const ushort* base = lo_src ? A_l : A_h;
      async16(base + (long)(m0 + row) * lda + k0 + lck, dst + seg * 512);
    }
#pragma unroll
    for (int s = 0; s < 2; ++s) {              // B: 16 segs / 8 waves
      const int seg = wave * 2 + s;            // [0,16)
      const int row = seg * 8 + lrow;          // [0,128)
      const ushort* base = lo_src ? B_l : B_h;
      async16(base + (long)(n0 + row) * ldb + k0 + lck, dst + 16384 + seg * 512);
    }
  };

  const int T = KK >> 5;                       // 32 K-tiles
  STAGE(0, 0);                                 // prologue (latency exposed once)

  for (int t = 0; t < T; ++t) {
    const int db = t & 1;
    asm volatile("s_waitcnt vmcnt(0)" ::: "memory");   // tile t landed (own)
    __builtin_amdgcn_s_barrier();              // all waves -> buf[db] ready
    if (t + 1 < T) STAGE(db ^ 1, t + 1);       // in flight for a full tile

    const ushort* sA = smem + db * 24576;
    const ushort* sB = sA + 16384;
    bfrag ah[4], al[4], bh[4], bl[4];
#pragma unroll
    for (int f = 0; f < 4; ++f) {
      const int arow = (wm + f * 16 + r16) * 64;
      const int brow = (wn + f * 16 + r16) * 64;
      ah[f] = *(const bfrag*)&sA[arow + ((quad ^ rk)) * 8];
      al[f] = *(const bfrag*)&sA[arow + (((quad + 4) ^ rk)) * 8];
      bh[f] = *(const bfrag*)&sB[brow + ((quad ^ rk)) * 8];
      bl[f] = *(const bfrag*)&sB[brow + (((quad + 4) ^ rk)) * 8];
    }

    __builtin_amdgcn_s_setprio(1);
#pragma unroll
    for (int mt = 0; mt < 2; ++mt)
#pragma unroll
      for (int nt = 0; nt < 4; ++nt) {
        acc[mt][nt] = __builtin_amdgcn_mfma_f32_16x16x32_bf16(ah[mt], bh[nt], acc[mt][nt], 0, 0, 0);
        acc[mt][nt] = __builtin_amdgcn_mfma_f32_16x16x32_bf16(ah[mt], bl[nt], acc[mt][nt], 0, 0, 0);
        acc[mt][nt] = __builtin_amdgcn_mfma_f32_16x16x32_bf16(al[mt], bh[nt], acc[mt][nt], 0, 0, 0);
      }
    __builtin_amdgcn_s_setprio(0);
    __builtin_amdgcn_s_barrier();              // phase-lock mid-tile
    __builtin_amdgcn_s_setprio(1);
#pragma unroll
    for (int mt = 2; mt < 4; ++mt)
#pragma unroll
      for (int nt = 0; nt < 4; ++nt) {
        acc[mt][nt] = __builtin_amdgcn_mfma_f32_16x16x32_bf16(ah[mt], bh[nt], acc[mt][nt], 0, 0, 0);
        acc[mt][nt] = __builtin_amdgcn_mfma_f32_16x16x32_bf16(ah[mt], bl[nt], acc[mt][nt], 0, 0, 0);
        acc[mt][nt] = __builtin_amdgcn_mfma_f32_16x16x32_bf16(al[mt], bh[nt], acc[mt][nt], 0, 0, 0);
      }
    __builtin_amdgcn_s_setprio(0);
  }

  // epilogue
#pragma unroll
  for (int mt = 0; mt < 4; ++mt)
#pragma unroll
    for (int nt = 0; nt < 4; ++nt)
#pragma unroll
      for (int reg = 0; reg < 4; ++reg) {
        const int ml = wm + mt * 16 + quad * 4 + reg;   // [0,256)
        const int nl = wn + nt * 16 + r16;              // [0,128)
        const float v = acc[mt][nt][reg];
        if (MODE == 0) {
          ushort* Ch = (ushort*)C0 + (long)b * bC;
          ushort* Cl = (ushort*)C1 + (long)b * bC;
          const long o = (long)(m0 + ml) * ldc + n0 + nl;
          const ushort h = f2b(v);
          Ch[o] = h;
          Cl[o] = f2b(v - b2f(h));
        } else {
          const int gi = m0 + ml;                       // row in batch
          const int ti = gi >> 7;
          if (tj <= ti) {
            float* C = (float*)C0 + (long)b * bC;
            C[(long)(ti * (ti + 1) / 2 + tj) * TRI_ELEMS + (gi & 127) * 128 + nl] = v;
          }
        }
      }
}

// ---------------------------------------------------------------------------
// bf16 MFMA GEMM (round-0 structure, proven 0-conflict): 128x128 block tile,
// 4 waves (2x2) of 64x64, BK=64, 16x16x32 MFMA, global_load_lds(16B) into
// swizzled LDS [128][64] (phys chunk = logical ^ (row&7)). Used for the two
// plain GEMMs (steps 5, 6) only.
// TRIA : A staged from triangular tile layout; K limited to m0+128.
// SWIZ 3: causal-balanced XCD map;  SWIZ 4: swapped-role XCD map.
// STORE 2: bf16 row-major;  STORE 3: fp32 row-major + residual from Res.
// ---------------------------------------------------------------------------
template <int SPLIT, int TRIA, int STORE, int SWIZ>
__global__ __launch_bounds__(256) void gemm_mfma(
    const ushort* __restrict__ Ah, const ushort* __restrict__ Al,
    const ushort* __restrict__ Bh, const ushort* __restrict__ Bl,
    void* __restrict__ C0, void* __restrict__ C1, const float* __restrict__ Res,
    int K, int lda, int ldb, int ldc,
    long bA, long bB, long bC, long bR) {
  extern __shared__ ushort smem[];
  ushort* sAh = smem;                                    // [128][64] 16KB
  ushort* sBh = smem + (SPLIT ? 16384 : 8192);
  ushort* sAl = SPLIT ? smem + 8192 : nullptr;
  ushort* sBl = SPLIT ? smem + 24576 : nullptr;

  int b, m0, n0, tiC = 0;
  if (SWIZ == 2) {
    const int g = (blockIdx.x & 7) * 68 + (blockIdx.x >> 3);
    b = g / NTRI;
    int t = g - b * NTRI;
    int ti = 0;
    while ((ti + 1) * (ti + 2) / 2 <= t) ++ti;
    const int tj = t - ti * (ti + 1) / 2;
    m0 = ti * 128; n0 = tj * 128; tiC = t;
  } else if (SWIZ == 1) {
    const int g = (blockIdx.x & 7) * 64 + (blockIdx.x >> 3);
    const int P = g >> 3;
    b = P >> 4;
    m0 = (P & 15) * 128;
    n0 = (g & 7) * 128;
  } else if (SWIZ == 3) {
    const int xcd = blockIdx.x & 7;
    const int idx = blockIdx.x >> 3;      // [0,64)
    const int q = idx >> 3;               // [0,8)
    b = q >> 1;
    const int mt_ = (q & 1) ? (15 - xcd) : xcd;
    m0 = mt_ * 128;
    n0 = (idx & 7) * 128;
  } else {  // SWIZ == 4
    const int g = (blockIdx.x & 7) * 64 + (blockIdx.x >> 3);
    const int P = g >> 3;
    b = P >> 4;
    n0 = (P & 15) * 128;
    m0 = (g & 7) * 128;
  }
  const int kmax = TRIA ? (m0 + 128) : K;
  int triA0 = 0;
  if (TRIA) { const int ti = m0 >> 7; triA0 = ti * (ti + 1) / 2; }

  const ushort* A_h = Ah + (long)b * bA;
  const ushort* B_h = Bh + (long)b * bB;
  const ushort* A_l = SPLIT ? Al + (long)b * bA : nullptr;
  const ushort* B_l = SPLIT ? Bl + (long)b * bB : nullptr;

  const int tid = threadIdx.x;
  const int lane = tid & 63, wave = tid >> 6;
  const int wm = (wave & 1) * 64, wn = (wave >> 1) * 64;
  const int r16 = lane & 15, quad = lane >> 4;
  // staging: 8 chunks of 8 bf16 per 128B row; logical chunk for this lane
  const int kc = ((lane & 7) ^ (lane >> 3)) * 8;
  const int lrow = lane >> 3;                            // [0,8)

  f32x4 acc[4][4];
#pragma unroll
  for (int i = 0; i < 4; ++i)
#pragma unroll
    for (int j = 0; j < 4; ++j) acc[i][j] = (f32x4){0.f, 0.f, 0.f, 0.f};

  for (int k0 = 0; k0 < kmax; k0 += 64) {
    __syncthreads();
    {
#pragma unroll
      for (int c = 0; c < 4; ++c) {
        const int seg = wave * 4 + c;     // [0,16): 8-row group
        const int row = seg * 8 + lrow;
        long aoff;
        if (TRIA)
          aoff = (long)(triA0 + (k0 >> 7)) * TRI_ELEMS + (long)row * 128 + (k0 & 127) + kc;
        else
          aoff = (long)(m0 + row) * lda + k0 + kc;
        const long boff = (long)(n0 + row) * ldb + k0 + kc;
        async16(A_h + aoff, sAh + seg * 512);
        async16(B_h + boff, sBh + seg * 512);
        if (SPLIT) {
          async16(A_l + aoff, sAl + seg * 512);
          async16(B_l + boff, sBl + seg * 512);
        }
      }
    }
    __syncthreads();

    const int sw = r16 & 7;
#pragma unroll
    for (int ksub = 0; ksub < 2; ++ksub) {
      const int ch = ((ksub * 4 + quad) ^ sw) * 8;       // physical chunk
      bfrag ah[4], bh[4], al[4], bl[4];
#pragma unroll
      for (int t4 = 0; t4 < 4; ++t4) {
        ah[t4] = *(const bfrag*)&sAh[(wm + t4 * 16 + r16) * 64 + ch];
        bh[t4] = *(const bfrag*)&sBh[(wn + t4 * 16 + r16) * 64 + ch];
        if (SPLIT) {
          al[t4] = *(const bfrag*)&sAl[(wm + t4 * 16 + r16) * 64 + ch];
          bl[t4] = *(const bfrag*)&sBl[(wn + t4 * 16 + r16) * 64 + ch];
        }
      }
#pragma unroll
      for (int mt = 0; mt < 4; ++mt)
#pragma unroll
        for (int nt = 0; nt < 4; ++nt) {
          acc[mt][nt] = __builtin_amdgcn_mfma_f32_16x16x32_bf16(ah[mt], bh[nt], acc[mt][nt], 0, 0, 0);
          if (SPLIT) {
            acc[mt][nt] = __builtin_amdgcn_mfma_f32_16x16x32_bf16(ah[mt], bl[nt], acc[mt][nt], 0, 0, 0);
            acc[mt][nt] = __builtin_amdgcn_mfma_f32_16x16x32_bf16(al[mt], bh[nt], acc[mt][nt], 0, 0, 0);
          }
        }
    }
  }

  // epilogue
#pragma unroll
  for (int mt = 0; mt < 4; ++mt)
#pragma unroll
    for (int nt = 0; nt < 4; ++nt)
#pragma unroll
      for (int reg = 0; reg < 4; ++reg) {
        const int ml = wm + mt * 16 + quad * 4 + reg;
        const int nl = wn + nt * 16 + r16;
        const float v = acc[mt][nt][reg];
        if (STORE == 0) {
          ushort* Ch = (ushort*)C0 + (long)b * bC;
          ushort* Cl = (ushort*)C1 + (long)b * bC;
          const long o = (long)(m0 + ml) * ldc + n0 + nl;
          const ushort h = f2b(v);
          Ch[o] = h;
          Cl[o] = f2b(v - b2f(h));
        } else if (STORE == 1) {
          float* C = (float*)C0 + (long)b * bC + (long)tiC * TRI_ELEMS;
          C[ml * 128 + nl] = v;
        } else if (STORE == 2) {
          ushort* C = (ushort*)C0 + (long)b * bC;
          C[(long)(m0 + ml) * ldc + n0 + nl] = f2b(v);
        } else {
          float* C = (float*)C0 + (long)b * bC;
          const float* R = Res + (long)b * bR;
          const long o = (long)(m0 + ml) * ldc + n0 + nl;
          C[o] = R[o] + v;
        }
      }
}

// ---------------------------------------------------------------------------
// Causal softmax over triangular-tiled logits. One block per row (b, i).
// Writes bf16 A in tri layout, zero-filling diagonal-tile cols beyond i.
// ---------------------------------------------------------------------------
__global__ __launch_bounds__(256) void softmax_tri(
    const float* __restrict__ L, ushort* __restrict__ Aout) {
  const int row = blockIdx.x;
  const int b = row >> 11, i = row & (NN - 1);
  const int ti = i >> 7, ml = i & 127;
  const long base = (long)b * ((long)NTRI * TRI_ELEMS);
  const int trib = ti * (ti + 1) / 2;
  const int len = i + 1;
  const int tot = (ti + 1) * 128;
  const int tid = threadIdx.x;
  __shared__ float red[256];
  float vv[8];
  float m = -INFINITY;
#pragma unroll
  for (int u = 0; u < 8; ++u) {
    const int j = tid + u * 256;
    if (j < len) {
      const float v = L[base + (long)(trib + (j >> 7)) * TRI_ELEMS + ml * 128 + (j & 127)];
      vv[u] = v;
      m = fmaxf(m, v);
    }
  }
  red[tid] = m; __syncthreads();
  for (int s = 128; s; s >>= 1) { if (tid < s) red[tid] = fmaxf(red[tid], red[tid + s]); __syncthreads(); }
  m = red[0]; __syncthreads();
  float sum = 0.f;
#pragma unroll
  for (int u = 0; u < 8; ++u) {
    const int j = tid + u * 256;
    if (j < len) { const float e = __expf(vv[u] - m); vv[u] = e; sum += e; }
  }
  red[tid] = sum; __syncthreads();
  for (int s = 128; s; s >>= 1) { if (tid < s) red[tid] += red[tid + s]; __syncthreads(); }
  const float inv = 1.f / red[0];
#pragma unroll
  for (int u = 0; u < 8; ++u) {
    const int j = tid + u * 256;
    if (j < tot) {
      const ushort o = (j < len) ? f2b(vv[u] * inv) : (ushort)0;
      Aout[base + (long)(trib + (j >> 7)) * TRI_ELEMS + ml * 128 + (j & 127)] = o;
    }
  }
}

// ---------------------------------------------------------------------------
// Pipeline (all MFMA operands k-contiguous by construction):
//  0. prep: x -> x_hi, xT hi/lo; W_Q..W_O -> WT [d][k] bf16     (1 dispatch)
//  1. gemm_w: Mqk (split) + Mov (plain) in one 512-block dispatch
//  2. tT[i,d] = sum_e xT[i,e] Mqk[d,e]      gemm_split8<0>, 256 blocks
//  3. logits[i,j] = sum_d xT[i,d] tT[j,d]   gemm_split8<1>, 288 blocks (tri)
//  4. A = causal softmax (bf16, tri layout, zero-padded diag tiles)
//  5. ctxT[i,e] = sum_{t<=i} A[i,t] x[e,t]  bf16 MFMA, causal K, SWIZ=3 (bal)
//  6. out[d,i] = x[d,i] + sum_e Mov[d,e] ctxT[i,e]   bf16 MFMA + res, SWIZ=4
// ---------------------------------------------------------------------------
extern "C" void kernel_launch(void* const* d_in, const int* in_sizes, int n_in,
                              void* d_out, int out_size, void* d_ws, size_t ws_size,
                              hipStream_t stream) {
  const float* x = (const float*)d_in[0];
  const float* WQ = (const float*)d_in[1];
  const float* WK = (const float*)d_in[2];
  const float* WV = (const float*)d_in[3];
  const float* WO = (const float*)d_in[4];
  float* out = (float*)d_out;

  const long XE = (long)BB * DD * NN;    // 8M elements
  const long WE = (long)DD * KK;         // 1M elements
  ushort* x_hi = (ushort*)d_ws;
  ushort* xTh = x_hi + XE;
  ushort* xTl = xTh + XE;
  ushort* wqT_h = xTl + XE;
  ushort* wqT_l = wqT_h + WE;
  ushort* wkT_h = wqT_l + WE;
  ushort* wkT_l = wkT_h + WE;
  ushort* wvT_h = wkT_l + WE;
  ushort* woT_h = wvT_h + WE;
  ushort* mqk_h = woT_h + WE;
  ushort* mqk_l = mqk_h + WE;
  ushort* mov_h = mqk_l + WE;
  ushort* tTh = mov_h + WE;
  ushort* tTl = tTh + XE;
  float* logits = (float*)(tTl + XE);    // B*NTRI*TRI_ELEMS fp32 (~35.7MB)
  ushort* A_tri = tTh;                   // overlays tT hi+lo (dead after step 3)
  ushort* ctxT = (ushort*)logits;        // overlays logits (dead after softmax)
  const long TRIB = (long)NTRI * TRI_ELEMS;
  const long XB = XE / BB;

  prep<<<dim3(64, 32, 6), dim3(32, 8), 0, stream>>>(
      x, WQ, WK, WV, WO, x_hi, xTh, xTl,
      wqT_h, wqT_l, wkT_h, wkT_l, wvT_h, woT_h);

  // Mqk (split) + Mov (plain), merged 64-tile dispatch
  gemm_w<<<dim3(512), 256, 16384, stream>>>(
      wqT_h, wqT_l, wkT_h, wkT_l, wvT_h, woT_h, mqk_h, mqk_l, mov_h);

  // tT = xT * Mqk^T (split, phased 8-wave, 256x128 tiles)
  gemm_split8<0><<<dim3(256), dim3(512), 0, stream>>>(
      xTh, xTl, mqk_h, mqk_l, tTh, tTl,
      DD, DD, DD, XB, 0, XB);

  // logits (lower tri, phased 8-wave, 256x128 tiles)
  gemm_split8<1><<<dim3(288), dim3(512), 0, stream>>>(
      xTh, xTl, tTh, tTl, logits, nullptr,
      DD, DD, 0, XB, XB, TRIB);

  softmax_tri<<<dim3(BB * NN), 256, 0, stream>>>(logits, A_tri);

  // ctxT = A * x^T (tri A, causal K-limit, balanced XCD swizzle)
  gemm_mfma<0, 1, 2, 3><<<dim3(512), 256, 32768, stream>>>(
      A_tri, nullptr, x_hi, nullptr, ctxT, nullptr, nullptr,
      NN, 0, NN, DD, TRIB, XB, XB, 0);

  // out = x + Mov * ctx (SWIZ=4: M=8 d-tiles, N=16 i-tiles)
  gemm_mfma<0, 0, 3, 4><<<dim3(512), 256, 32768, stream>>>(
      mov_h, nullptr, ctxT, nullptr, out, nullptr, x,
      DD, DD, DD, NN, 0, XB, XB, XB);
}

// Round 3
// 341.812 us; speedup vs baseline: 1.0255x; 1.0238x over previous
//
#include <hip/hip_runtime.h>
#include <hip/hip_bf16.h>
#include <math.h>

// Problem constants: B=4, D=1024, N=2048, K=1024, fp32 in/out.
#define BB 4
#define DD 1024
#define NN 2048
#define KK 1024
#define NT128 16            // NN/128
#define NTRI 136            // 16*17/2 lower-triangular 128x128 tiles
#define TRI_ELEMS 16384     // 128*128

typedef __attribute__((ext_vector_type(4))) float f32x4;
typedef __attribute__((ext_vector_type(8))) short bfrag;

typedef __attribute__((address_space(1))) const unsigned int gu32;
typedef __attribute__((address_space(3))) unsigned int lu32;

// async global->LDS, 16B per lane; LDS dest = base + lane*16 (wave-uniform base)
__device__ __forceinline__ void async16(const void* g, void* l) {
  __builtin_amdgcn_global_load_lds((gu32*)g, (lu32*)l, 16, 0, 0);
}

__device__ __forceinline__ ushort f2b(float f) {  // fp32 -> bf16 RNE
  union { float f; unsigned u; } c; c.f = f;
  unsigned u = c.u + 0x7fffu + ((c.u >> 16) & 1u);
  return (ushort)(u >> 16);
}
__device__ __forceinline__ float b2f(ushort h) {
  union { unsigned u; float f; } c; c.u = ((unsigned)h) << 16;
  return c.f;
}

// ---------------------------------------------------------------------------
// prep: merged input transform, grid (64, 32, 6), block (32,8).
//  z<4 : x [b=z][d][n] fp32 -> x_hi (bf16 same layout), xT hi/lo ([b][n][d])
//  z>=4: weight w = (z-4)*2 + (bx>>5): W (K x D, [k][d]) -> WT [d][k] bf16
//        (WQ, WK split hi+lo; WV, WO hi only)
// ---------------------------------------------------------------------------
__global__ __launch_bounds__(256) void prep(
    const float* __restrict__ x,
    const float* __restrict__ WQ, const float* __restrict__ WK,
    const float* __restrict__ WV, const float* __restrict__ WO,
    ushort* __restrict__ xhi, ushort* __restrict__ xTh, ushort* __restrict__ xTl,
    ushort* __restrict__ qh, ushort* __restrict__ ql,
    ushort* __restrict__ kh, ushort* __restrict__ kl_,
    ushort* __restrict__ vh, ushort* __restrict__ oh) {
  const int z = blockIdx.z;
  const int tx = threadIdx.x, ty = threadIdx.y;
  __shared__ float tile[32][33];
  if (z < 4) {
    const int b = z;
    const int n0 = blockIdx.x * 32, d0 = blockIdx.y * 32;
    const float* xb = x + (long)b * DD * NN;
    ushort* xhb = xhi + (long)b * DD * NN;
#pragma unroll
    for (int r = 0; r < 4; ++r) {
      const int dl = ty + r * 8;
      const float v = xb[(long)(d0 + dl) * NN + n0 + tx];
      tile[dl][tx] = v;
      xhb[(long)(d0 + dl) * NN + n0 + tx] = f2b(v);
    }
    __syncthreads();
#pragma unroll
    for (int r = 0; r < 4; ++r) {
      const int nl = ty + r * 8;
      const float v = tile[tx][nl];
      const ushort h = f2b(v);
      const long o = (long)b * NN * DD + (long)(n0 + nl) * DD + d0 + tx;
      xTh[o] = h;
      xTl[o] = f2b(v - b2f(h));
    }
  } else {
    const int w = (z - 4) * 2 + (blockIdx.x >> 5);
    const float* W = (w == 0) ? WQ : (w == 1) ? WK : (w == 2) ? WV : WO;
    ushort* Th = (w == 0) ? qh : (w == 1) ? kh : (w == 2) ? vh : oh;
    ushort* Tl = (w == 0) ? ql : (w == 1) ? kl_ : nullptr;
    const int k0 = (blockIdx.x & 31) * 32, d0 = blockIdx.y * 32;
#pragma unroll
    for (int r = 0; r < 4; ++r) {
      const int kl = ty + r * 8;
      tile[kl][tx] = W[(long)(k0 + kl) * DD + d0 + tx];
    }
    __syncthreads();
#pragma unroll
    for (int r = 0; r < 4; ++r) {
      const int dl = ty + r * 8;
      const float v = tile[tx][dl];              // = W[k0+tx][d0+dl]
      const ushort h = f2b(v);
      const long o = (long)(d0 + dl) * KK + k0 + tx;
      Th[o] = h;
      if (Tl) Tl[o] = f2b(v - b2f(h));
    }
  }
}

// ---------------------------------------------------------------------------
// Merged weight-product GEMM, 64x64 tiles, BK=32, 512 blocks:
//   id<256 : Mqk[m,n] = sum_k wqT[m,k] wkT[n,k]  (split 3-MFMA, split store)
//   id>=256: Mov[m,n] = sum_k woT[m,k] wvT[n,k]  (plain bf16)
// ---------------------------------------------------------------------------
__global__ __launch_bounds__(256) void gemm_w(
    const ushort* __restrict__ qh, const ushort* __restrict__ ql,
    const ushort* __restrict__ kh, const ushort* __restrict__ kl_,
    const ushort* __restrict__ vh, const ushort* __restrict__ oh,
    ushort* __restrict__ mqk_h, ushort* __restrict__ mqk_l,
    ushort* __restrict__ mov_h) {
  extern __shared__ ushort smem[];
  ushort* sAh = smem;            // [64][32] 4KB
  ushort* sAl = smem + 2048;
  ushort* sBh = smem + 4096;
  ushort* sBl = smem + 6144;

  const int id = blockIdx.x;
  const int half = id >> 8;                  // 0 = Mqk (split), 1 = Mov (plain)
  const int t = id & 255;
  const int m0 = (t >> 4) * 64, n0 = (t & 15) * 64;
  const ushort* A_h = half ? oh : qh;
  const ushort* B_h = half ? vh : kh;

  const int tid = threadIdx.x;
  const int lane = tid & 63, wave = tid >> 6;
  const int wm = (wave & 1) * 32, wn = (wave >> 1) * 32;
  const int r16 = lane & 15, quad = lane >> 4;
  const int kc = ((lane & 3) ^ ((lane >> 3) & 3)) * 8;   // swizzled k-chunk
  const int srow = lane >> 2;

  f32x4 acc[2][2];
#pragma unroll
  for (int i = 0; i < 2; ++i)
#pragma unroll
    for (int j = 0; j < 2; ++j) acc[i][j] = (f32x4){0.f, 0.f, 0.f, 0.f};

  for (int k0 = 0; k0 < KK; k0 += 32) {
    __syncthreads();
    {
      const int row = wave * 16 + srow;
      const long aoff = (long)(m0 + row) * KK + k0 + kc;
      const long boff = (long)(n0 + row) * KK + k0 + kc;
      async16(A_h + aoff, sAh + wave * 512);
      async16(B_h + boff, sBh + wave * 512);
      if (half == 0) {
        async16(ql + aoff, sAl + wave * 512);
        async16(kl_ + boff, sBl + wave * 512);
      }
    }
    __syncthreads();

    const int sw = (r16 >> 1) & 3;
    bfrag ah[2], bh[2], al[2], bl[2];
#pragma unroll
    for (int t2 = 0; t2 < 2; ++t2) {
      ah[t2] = *(const bfrag*)&sAh[(wm + t2 * 16 + r16) * 32 + (quad ^ sw) * 8];
      bh[t2] = *(const bfrag*)&sBh[(wn + t2 * 16 + r16) * 32 + (quad ^ sw) * 8];
      if (half == 0) {
        al[t2] = *(const bfrag*)&sAl[(wm + t2 * 16 + r16) * 32 + (quad ^ sw) * 8];
        bl[t2] = *(const bfrag*)&sBl[(wn + t2 * 16 + r16) * 32 + (quad ^ sw) * 8];
      }
    }
#pragma unroll
    for (int mt = 0; mt < 2; ++mt)
#pragma unroll
      for (int nt = 0; nt < 2; ++nt) {
        acc[mt][nt] = __builtin_amdgcn_mfma_f32_16x16x32_bf16(ah[mt], bh[nt], acc[mt][nt], 0, 0, 0);
        if (half == 0) {
          acc[mt][nt] = __builtin_amdgcn_mfma_f32_16x16x32_bf16(ah[mt], bl[nt], acc[mt][nt], 0, 0, 0);
          acc[mt][nt] = __builtin_amdgcn_mfma_f32_16x16x32_bf16(al[mt], bh[nt], acc[mt][nt], 0, 0, 0);
        }
      }
  }

#pragma unroll
  for (int mt = 0; mt < 2; ++mt)
#pragma unroll
    for (int nt = 0; nt < 2; ++nt)
#pragma unroll
      for (int reg = 0; reg < 4; ++reg) {
        const int ml = wm + mt * 16 + quad * 4 + reg;
        const int nl = wn + nt * 16 + r16;
        const float v = acc[mt][nt][reg];
        const long o = (long)(m0 + ml) * DD + n0 + nl;
        if (half == 0) {
          const ushort h = f2b(v);
          mqk_h[o] = h;
          mqk_l[o] = f2b(v - b2f(h));
        } else {
          mov_h[o] = f2b(v);
        }
      }
}

// ---------------------------------------------------------------------------
// gemm_split8: the two big split GEMMs, DEPTH-3 pipeline (true T3/T4 regime:
// every tile's loads have ~2 full tiles of MFMA to land under; vmcnt never
// drains in the main loop; ONE barrier per tile, no lockstep mid-barrier).
//   Tile 256x128, BK=32, 8 waves (512 thr) as 4m x 2n -> per-wave 64x64.
//   LDS: static 144KB = 3 buffers x (A[256][64] 32KB + B[128][64] 16KB).
//   hi|lo PACKED per row: 128B row = 8 chunks of 16B; chunks 0-3 = hi
//   k-chunks, 4-7 = lo; bank swizzle physical chunk = logical ^ (row&7)
//   (verified 0 conflicts in R2). Staging realizes the swizzle by
//   pre-swizzling the per-lane GLOBAL source (LDS dest linear, m104/m173).
// Schedule per K-tile t (buf = t%3), 1 barrier/tile:
//   s_waitcnt vmcnt(6)   ; per-wave FIFO: 12 outstanding (t, t+1) -> drains
//                        ; exactly tile t's 6 loads, issued 2 tiles ago
//   s_barrier            ; all waves done staging tile t -> buf ready; also
//                        ; guarantees all waves' t-1 ds_reads consumed (each
//                        ; wave's MFMAs drained them before reaching here)
//   STAGE(t+2 -> buf[(t+2)%3])  ; overwrites buffer last read at t-1: safe
//   16 ds_reads of buf[t%3]
//   setprio(1); 48 MFMA; setprio(0)
// MODE 0: step 2 (tT = xT x Mqk^T), grid 256, split hi/lo bf16 store.
// MODE 1: step 3 (logits, lower-tri), grid 288, fp32 tri-tile store; block
//   covers 2 tri-rows (ti=2I, 2I+1); cols beyond diag (tj>ti) discarded.
// ---------------------------------------------------------------------------
template <int MODE>
__global__ __launch_bounds__(512, 2) void gemm_split8(
    const ushort* __restrict__ Ah, const ushort* __restrict__ Al,
    const ushort* __restrict__ Bh, const ushort* __restrict__ Bl,
    void* __restrict__ C0, void* __restrict__ C1,
    int lda, int ldb, int ldc, long bA, long bB, long bC) {
  __shared__ ushort smem[73728];               // 3 x 24576 elems = 144KB

  int b, m0, n0, tj = 0;
  if (MODE == 0) {
    // 256 blocks: g = xcd-chunked; I in [0,32) -> (b, m0), n0 = 8 j-tiles
    const int g = (blockIdx.x & 7) * 32 + (blockIdx.x >> 3);
    const int I = g >> 3;
    b = I >> 3;
    m0 = (I & 7) * 256;
    n0 = (g & 7) * 128;
  } else {
    // 288 blocks: per batch 72 = sum_{I<8}(2I+2) blocks, jt <= 2I+1
    const int g = (blockIdx.x & 7) * 36 + (blockIdx.x >> 3);
    b = g / 72;
    const int r = g - b * 72;
    int I = 0;
    while ((I + 1) * (I + 2) <= r) ++I;        // prefix(I) = I*(I+1)
    const int jt = r - I * (I + 1);
    m0 = I * 256;
    n0 = jt * 128;
    tj = jt;
  }

  const ushort* A_h = Ah + (long)b * bA;
  const ushort* A_l = Al + (long)b * bA;
  const ushort* B_h = Bh + (long)b * bB;
  const ushort* B_l = Bl + (long)b * bB;

  const int tid = threadIdx.x;
  const int lane = tid & 63, wave = tid >> 6;  // wave in [0,8)
  const int wm = (wave & 3) * 64, wn = (wave >> 2) * 64;
  const int r16 = lane & 15, quad = lane >> 4;
  const int rk = r16 & 7;                      // row&7 for frag reads

  // staging lane mapping: 8 rows x 8 phys chunks per async16 (1KB)
  const int lrow = lane >> 3;                  // row within 8-row segment
  const int lc = (lane & 7) ^ lrow;            // logical chunk = phys ^ row&7
  const int lck = (lc & 3) * 8;                // k-offset of the chunk
  const bool lo_src = lc >= 4;                 // chunks 4-7 come from *_l

  f32x4 acc[4][4];
#pragma unroll
  for (int i = 0; i < 4; ++i)
#pragma unroll
    for (int j = 0; j < 4; ++j) acc[i][j] = (f32x4){0.f, 0.f, 0.f, 0.f};

  auto STAGE = [&](int db, int t) {
    const int k0 = t << 5;
    ushort* dst = smem + db * 24576;
#pragma unroll
    for (int s = 0; s < 4; ++s) {              // A: 32 segs / 8 waves
      const int seg = wave * 4 + s;            // [0,32)
      const int row = seg * 8 + lrow;          // [0,256)
      const ushort* base = lo_src ? A_l : A_h;
      async16(base + (long)(m0 + row) * lda + k0 + lck, dst + seg * 512);
    }
#pragma unroll
    for (int s = 0; s < 2; ++s) {              // B: 16 segs / 8 waves
      const int seg = wave * 2 + s;            // [0,16)
      const int row = seg * 8 + lrow;          // [0,128)
      const ushort* base = lo_src ? B_l : B_h;
      async16(base + (long)(n0 + row) * ldb + k0 + lck, dst + 16384 + seg * 512);
    }
  };

  const int T = KK >> 5;                       // 32 K-tiles
  STAGE(0, 0);                                 // prologue: 2 tiles in flight
  STAGE(1, 1);

  for (int t = 0; t < T; ++t) {
    const int buf = t % 3;
    if (t + 1 < T) {
      // 12 outstanding per wave (tiles t, t+1); drain to 6 = tile t done.
      asm volatile("s_waitcnt vmcnt(6)" ::: "memory");
    } else {
      asm volatile("s_waitcnt vmcnt(0)" ::: "memory");
    }
    __builtin_amdgcn_s_barrier();              // buf ready; t-1 reads consumed
    if (t + 2 < T) STAGE((t + 2) % 3, t + 2);  // ~2 tiles of slack to land

    const ushort* sA = smem + buf * 24576;
    const ushort* sB = sA + 16384;
    bfrag ah[4], al[4], bh[4], bl[4];
#pragma unroll
    for (int f = 0; f < 4; ++f) {
      const int arow = (wm + f * 16 + r16) * 64;
      const int brow = (wn + f * 16 + r16) * 64;
      ah[f] = *(const bfrag*)&sA[arow + ((quad ^ rk)) * 8];
      al[f] = *(const bfrag*)&sA[arow + (((quad + 4) ^ rk)) * 8];
      bh[f] = *(const bfrag*)&sB[brow + ((quad ^ rk)) * 8];
      bl[f] = *(const bfrag*)&sB[brow + (((quad + 4) ^ rk)) * 8];
    }

    __builtin_amdgcn_s_setprio(1);
#pragma unroll
    for (int mt = 0; mt < 4; ++mt)
#pragma unroll
      for (int nt = 0; nt < 4; ++nt) {
        acc[mt][nt] = __builtin_amdgcn_mfma_f32_16x16x32_bf16(ah[mt], bh[nt], acc[mt][nt], 0, 0, 0);
        acc[mt][nt] = __builtin_amdgcn_mfma_f32_16x16x32_bf16(ah[mt], bl[nt], acc[mt][nt], 0, 0, 0);
        acc[mt][nt] = __builtin_amdgcn_mfma_f32_16x16x32_bf16(al[mt], bh[nt], acc[mt][nt], 0, 0, 0);
      }
    __builtin_amdgcn_s_setprio(0);
  }

  // epilogue
#pragma unroll
  for (int mt = 0; mt < 4; ++mt)
#pragma unroll
    for (int nt = 0; nt < 4; ++nt)
#pragma unroll
      for (int reg = 0; reg < 4; ++reg) {
        const int ml = wm + mt * 16 + quad * 4 + reg;   // [0,256)
        const int nl = wn + nt * 16 + r16;              // [0,128)
        const float v = acc[mt][nt][reg];
        if (MODE == 0) {
          ushort* Ch = (ushort*)C0 + (long)b * bC;
          ushort* Cl = (ushort*)C1 + (long)b * bC;
          const long o = (long)(m0 + ml) * ldc + n0 + nl;
          const ushort h = f2b(v);
          Ch[o] = h;
          Cl[o] = f2b(v - b2f(h));
        } else {
          const int gi = m0 + ml;                       // row in batch
          const int ti = gi >> 7;
          if (tj <= ti) {
            float* C = (float*)C0 + (long)b * bC;
            C[(long)(ti * (ti + 1) / 2 + tj) * TRI_ELEMS + (gi & 127) * 128 + nl] = v;
          }
        }
      }
}

// ---------------------------------------------------------------------------
// bf16 MFMA GEMM (round-0 structure, proven 0-conflict): 128x128 block tile,
// 4 waves (2x2) of 64x64, BK=64, 16x16x32 MFMA, global_load_lds(16B) into
// swizzled LDS [128][64] (phys chunk = logical ^ (row&7)). Used for the two
// plain GEMMs (steps 5, 6) only.
// TRIA : A staged from triangular tile layout; K limited to m0+128.
// SWIZ 3: causal-balanced XCD map;  SWIZ 4: swapped-role XCD map.
// STORE 2: bf16 row-major;  STORE 3: fp32 row-major + residual from Res.
// ---------------------------------------------------------------------------
template <int SPLIT, int TRIA, int STORE, int SWIZ>
__global__ __launch_bounds__(256) void gemm_mfma(
    const ushort* __restrict__ Ah, const ushort* __restrict__ Al,
    const ushort* __restrict__ Bh, const ushort* __restrict__ Bl,
    void* __restrict__ C0, void* __restrict__ C1, const float* __restrict__ Res,
    int K, int lda, int ldb, int ldc,
    long bA, long bB, long bC, long bR) {
  extern __shared__ ushort smem[];
  ushort* sAh = smem;                                    // [128][64] 16KB
  ushort* sBh = smem + (SPLIT ? 16384 : 8192);
  ushort* sAl = SPLIT ? smem + 8192 : nullptr;
  ushort* sBl = SPLIT ? smem + 24576 : nullptr;

  int b, m0, n0, tiC = 0;
  if (SWIZ == 2) {
    const int g = (blockIdx.x & 7) * 68 + (blockIdx.x >> 3);
    b = g / NTRI;
    int t = g - b * NTRI;
    int ti = 0;
    while ((ti + 1) * (ti + 2) / 2 <= t) ++ti;
    const int tj = t - ti * (ti + 1) / 2;
    m0 = ti * 128; n0 = tj * 128; tiC = t;
  } else if (SWIZ == 1) {
    const int g = (blockIdx.x & 7) * 64 + (blockIdx.x >> 3);
    const int P = g >> 3;
    b = P >> 4;
    m0 = (P & 15) * 128;
    n0 = (g & 7) * 128;
  } else if (SWIZ == 3) {
    const int xcd = blockIdx.x & 7;
    const int idx = blockIdx.x >> 3;      // [0,64)
    const int q = idx >> 3;               // [0,8)
    b = q >> 1;
    const int mt_ = (q & 1) ? (15 - xcd) : xcd;
    m0 = mt_ * 128;
    n0 = (idx & 7) * 128;
  } else {  // SWIZ == 4
    const int g = (blockIdx.x & 7) * 64 + (blockIdx.x >> 3);
    const int P = g >> 3;
    b = P >> 4;
    n0 = (P & 15) * 128;
    m0 = (g & 7) * 128;
  }
  const int kmax = TRIA ? (m0 + 128) : K;
  int triA0 = 0;
  if (TRIA) { const int ti = m0 >> 7; triA0 = ti * (ti + 1) / 2; }

  const ushort* A_h = Ah + (long)b * bA;
  const ushort* B_h = Bh + (long)b * bB;
  const ushort* A_l = SPLIT ? Al + (long)b * bA : nullptr;
  const ushort* B_l = SPLIT ? Bl + (long)b * bB : nullptr;

  const int tid = threadIdx.x;
  const int lane = tid & 63, wave = tid >> 6;
  const int wm = (wave & 1) * 64, wn = (wave >> 1) * 64;
  const int r16 = lane & 15, quad = lane >> 4;
  // staging: 8 chunks of 8 bf16 per 128B row; logical chunk for this lane
  const int kc = ((lane & 7) ^ (lane >> 3)) * 8;
  const int lrow = lane >> 3;                            // [0,8)

  f32x4 acc[4][4];
#pragma unroll
  for (int i = 0; i < 4; ++i)
#pragma unroll
    for (int j = 0; j < 4; ++j) acc[i][j] = (f32x4){0.f, 0.f, 0.f, 0.f};

  for (int k0 = 0; k0 < kmax; k0 += 64) {
    __syncthreads();
    {
#pragma unroll
      for (int c = 0; c < 4; ++c) {
        const int seg = wave * 4 + c;     // [0,16): 8-row group
        const int row = seg * 8 + lrow;
        long aoff;
        if (TRIA)
          aoff = (long)(triA0 + (k0 >> 7)) * TRI_ELEMS + (long)row * 128 + (k0 & 127) + kc;
        else
          aoff = (long)(m0 + row) * lda + k0 + kc;
        const long boff = (long)(n0 + row) * ldb + k0 + kc;
        async16(A_h + aoff, sAh + seg * 512);
        async16(B_h + boff, sBh + seg * 512);
        if (SPLIT) {
          async16(A_l + aoff, sAl + seg * 512);
          async16(B_l + boff, sBl + seg * 512);
        }
      }
    }
    __syncthreads();

    const int sw = r16 & 7;
#pragma unroll
    for (int ksub = 0; ksub < 2; ++ksub) {
      const int ch = ((ksub * 4 + quad) ^ sw) * 8;       // physical chunk
      bfrag ah[4], bh[4], al[4], bl[4];
#pragma unroll
      for (int t4 = 0; t4 < 4; ++t4) {
        ah[t4] = *(const bfrag*)&sAh[(wm + t4 * 16 + r16) * 64 + ch];
        bh[t4] = *(const bfrag*)&sBh[(wn + t4 * 16 + r16) * 64 + ch];
        if (SPLIT) {
          al[t4] = *(const bfrag*)&sAl[(wm + t4 * 16 + r16) * 64 + ch];
          bl[t4] = *(const bfrag*)&sBl[(wn + t4 * 16 + r16) * 64 + ch];
        }
      }
#pragma unroll
      for (int mt = 0; mt < 4; ++mt)
#pragma unroll
        for (int nt = 0; nt < 4; ++nt) {
          acc[mt][nt] = __builtin_amdgcn_mfma_f32_16x16x32_bf16(ah[mt], bh[nt], acc[mt][nt], 0, 0, 0);
          if (SPLIT) {
            acc[mt][nt] = __builtin_amdgcn_mfma_f32_16x16x32_bf16(ah[mt], bl[nt], acc[mt][nt], 0, 0, 0);
            acc[mt][nt] = __builtin_amdgcn_mfma_f32_16x16x32_bf16(al[mt], bh[nt], acc[mt][nt], 0, 0, 0);
          }
        }
    }
  }

  // epilogue
#pragma unroll
  for (int mt = 0; mt < 4; ++mt)
#pragma unroll
    for (int nt = 0; nt < 4; ++nt)
#pragma unroll
      for (int reg = 0; reg < 4; ++reg) {
        const int ml = wm + mt * 16 + quad * 4 + reg;
        const int nl = wn + nt * 16 + r16;
        const float v = acc[mt][nt][reg];
        if (STORE == 0) {
          ushort* Ch = (ushort*)C0 + (long)b * bC;
          ushort* Cl = (ushort*)C1 + (long)b * bC;
          const long o = (long)(m0 + ml) * ldc + n0 + nl;
          const ushort h = f2b(v);
          Ch[o] = h;
          Cl[o] = f2b(v - b2f(h));
        } else if (STORE == 1) {
          float* C = (float*)C0 + (long)b * bC + (long)tiC * TRI_ELEMS;
          C[ml * 128 + nl] = v;
        } else if (STORE == 2) {
          ushort* C = (ushort*)C0 + (long)b * bC;
          C[(long)(m0 + ml) * ldc + n0 + nl] = f2b(v);
        } else {
          float* C = (float*)C0 + (long)b * bC;
          const float* R = Res + (long)b * bR;
          const long o = (long)(m0 + ml) * ldc + n0 + nl;
          C[o] = R[o] + v;
        }
      }
}

// ---------------------------------------------------------------------------
// Causal softmax over triangular-tiled logits. One block per row (b, i).
// Writes bf16 A in tri layout, zero-filling diagonal-tile cols beyond i.
// ---------------------------------------------------------------------------
__global__ __launch_bounds__(256) void softmax_tri(
    const float* __restrict__ L, ushort* __restrict__ Aout) {
  const int row = blockIdx.x;
  const int b = row >> 11, i = row & (NN - 1);
  const int ti = i >> 7, ml = i & 127;
  const long base = (long)b * ((long)NTRI * TRI_ELEMS);
  const int trib = ti * (ti + 1) / 2;
  const int len = i + 1;
  const int tot = (ti + 1) * 128;
  const int tid = threadIdx.x;
  __shared__ float red[256];
  float vv[8];
  float m = -INFINITY;
#pragma unroll
  for (int u = 0; u < 8; ++u) {
    const int j = tid + u * 256;
    if (j < len) {
      const float v = L[base + (long)(trib + (j >> 7)) * TRI_ELEMS + ml * 128 + (j & 127)];
      vv[u] = v;
      m = fmaxf(m, v);
    }
  }
  red[tid] = m; __syncthreads();
  for (int s = 128; s; s >>= 1) { if (tid < s) red[tid] = fmaxf(red[tid], red[tid + s]); __syncthreads(); }
  m = red[0]; __syncthreads();
  float sum = 0.f;
#pragma unroll
  for (int u = 0; u < 8; ++u) {
    const int j = tid + u * 256;
    if (j < len) { const float e = __expf(vv[u] - m); vv[u] = e; sum += e; }
  }
  red[tid] = sum; __syncthreads();
  for (int s = 128; s; s >>= 1) { if (tid < s) red[tid] += red[tid + s]; __syncthreads(); }
  const float inv = 1.f / red[0];
#pragma unroll
  for (int u = 0; u < 8; ++u) {
    const int j = tid + u * 256;
    if (j < tot) {
      const ushort o = (j < len) ? f2b(vv[u] * inv) : (ushort)0;
      Aout[base + (long)(trib + (j >> 7)) * TRI_ELEMS + ml * 128 + (j & 127)] = o;
    }
  }
}

// ---------------------------------------------------------------------------
// Pipeline (all MFMA operands k-contiguous by construction):
//  0. prep: x -> x_hi, xT hi/lo; W_Q..W_O -> WT [d][k] bf16     (1 dispatch)
//  1. gemm_w: Mqk (split) + Mov (plain) in one 512-block dispatch
//  2. tT[i,d] = sum_e xT[i,e] Mqk[d,e]      gemm_split8<0>, 256 blocks
//  3. logits[i,j] = sum_d xT[i,d] tT[j,d]   gemm_split8<1>, 288 blocks (tri)
//  4. A = causal softmax (bf16, tri layout, zero-padded diag tiles)
//  5. ctxT[i,e] = sum_{t<=i} A[i,t] x[e,t]  bf16 MFMA, causal K, SWIZ=3 (bal)
//  6. out[d,i] = x[d,i] + sum_e Mov[d,e] ctxT[i,e]   bf16 MFMA + res, SWIZ=4
// ---------------------------------------------------------------------------
extern "C" void kernel_launch(void* const* d_in, const int* in_sizes, int n_in,
                              void* d_out, int out_size, void* d_ws, size_t ws_size,
                              hipStream_t stream) {
  const float* x = (const float*)d_in[0];
  const float* WQ = (const float*)d_in[1];
  const float* WK = (const float*)d_in[2];
  const float* WV = (const float*)d_in[3];
  const float* WO = (const float*)d_in[4];
  float* out = (float*)d_out;

  const long XE = (long)BB * DD * NN;    // 8M elements
  const long WE = (long)DD * KK;         // 1M elements
  ushort* x_hi = (ushort*)d_ws;
  ushort* xTh = x_hi + XE;
  ushort* xTl = xTh + XE;
  ushort* wqT_h = xTl + XE;
  ushort* wqT_l = wqT_h + WE;
  ushort* wkT_h = wqT_l + WE;
  ushort* wkT_l = wkT_h + WE;
  ushort* wvT_h = wkT_l + WE;
  ushort* woT_h = wvT_h + WE;
  ushort* mqk_h = woT_h + WE;
  ushort* mqk_l = mqk_h + WE;
  ushort* mov_h = mqk_l + WE;
  ushort* tTh = mov_h + WE;
  ushort* tTl = tTh + XE;
  float* logits = (float*)(tTl + XE);    // B*NTRI*TRI_ELEMS fp32 (~35.7MB)
  ushort* A_tri = tTh;                   // overlays tT hi+lo (dead after step 3)
  ushort* ctxT = (ushort*)logits;        // overlays logits (dead after softmax)
  const long TRIB = (long)NTRI * TRI_ELEMS;
  const long XB = XE / BB;

  prep<<<dim3(64, 32, 6), dim3(32, 8), 0, stream>>>(
      x, WQ, WK, WV, WO, x_hi, xTh, xTl,
      wqT_h, wqT_l, wkT_h, wkT_l, wvT_h, woT_h);

  // Mqk (split) + Mov (plain), merged 64-tile dispatch
  gemm_w<<<dim3(512), 256, 16384, stream>>>(
      wqT_h, wqT_l, wkT_h, wkT_l, wvT_h, woT_h, mqk_h, mqk_l, mov_h);

  // tT = xT * Mqk^T (split, depth-3 8-wave, 256x128 tiles)
  gemm_split8<0><<<dim3(256), dim3(512), 0, stream>>>(
      xTh, xTl, mqk_h, mqk_l, tTh, tTl,
      DD, DD, DD, XB, 0, XB);

  // logits (lower tri, depth-3 8-wave, 256x128 tiles)
  gemm_split8<1><<<dim3(288), dim3(512), 0, stream>>>(
      xTh, xTl, tTh, tTl, logits, nullptr,
      DD, DD, 0, XB, XB, TRIB);

  softmax_tri<<<dim3(BB * NN), 256, 0, stream>>>(logits, A_tri);

  // ctxT = A * x^T (tri A, causal K-limit, balanced XCD swizzle)
  gemm_mfma<0, 1, 2, 3><<<dim3(512), 256, 32768, stream>>>(
      A_tri, nullptr, x_hi, nullptr, ctxT, nullptr, nullptr,
      NN, 0, NN, DD, TRIB, XB, XB, 0);

  // out = x + Mov * ctx (SWIZ=4: M=8 d-tiles, N=16 i-tiles)
  gemm_mfma<0, 0, 3, 4><<<dim3(512), 256, 32768, stream>>>(
      mov_h, nullptr, ctxT, nullptr, out, nullptr, x,
      DD, DD, DD, NN, 0, XB, XB, XB);
}

// Round 4
// 327.622 us; speedup vs baseline: 1.0699x; 1.0433x over previous
//
#include <hip/hip_runtime.h>
#include <hip/hip_bf16.h>
#include <math.h>

// Problem constants: B=4, D=1024, N=2048, K=1024, fp32 in/out.
#define BB 4
#define DD 1024
#define NN 2048
#define KK 1024
#define NT128 16            // NN/128
#define NTRI 136            // 16*17/2 lower-triangular 128x128 tiles
#define TRI_ELEMS 16384     // 128*128

typedef __attribute__((ext_vector_type(4))) float f32x4;
typedef __attribute__((ext_vector_type(8))) short bfrag;

typedef __attribute__((address_space(1))) const unsigned int gu32;
typedef __attribute__((address_space(3))) unsigned int lu32;

// async global->LDS, 16B per lane; LDS dest = base + lane*16 (wave-uniform base)
__device__ __forceinline__ void async16(const void* g, void* l) {
  __builtin_amdgcn_global_load_lds((gu32*)g, (lu32*)l, 16, 0, 0);
}

__device__ __forceinline__ ushort f2b(float f) {  // fp32 -> bf16 RNE
  union { float f; unsigned u; } c; c.f = f;
  unsigned u = c.u + 0x7fffu + ((c.u >> 16) & 1u);
  return (ushort)(u >> 16);
}
__device__ __forceinline__ float b2f(ushort h) {
  union { unsigned u; float f; } c; c.u = ((unsigned)h) << 16;
  return c.f;
}

// ---------------------------------------------------------------------------
// prep: merged input transform, grid (64, 32, 6), block (32,8).
//  z<4 : x [b=z][d][n] fp32 -> x_hi (bf16 same layout), xT hi/lo ([b][n][d])
//  z>=4: weight w = (z-4)*2 + (bx>>5): W (K x D, [k][d]) -> WT [d][k] bf16
//        (WQ, WK split hi+lo; WV, WO hi only)
// ---------------------------------------------------------------------------
__global__ __launch_bounds__(256) void prep(
    const float* __restrict__ x,
    const float* __restrict__ WQ, const float* __restrict__ WK,
    const float* __restrict__ WV, const float* __restrict__ WO,
    ushort* __restrict__ xhi, ushort* __restrict__ xTh, ushort* __restrict__ xTl,
    ushort* __restrict__ qh, ushort* __restrict__ ql,
    ushort* __restrict__ kh, ushort* __restrict__ kl_,
    ushort* __restrict__ vh, ushort* __restrict__ oh) {
  const int z = blockIdx.z;
  const int tx = threadIdx.x, ty = threadIdx.y;
  __shared__ float tile[32][33];
  if (z < 4) {
    const int b = z;
    const int n0 = blockIdx.x * 32, d0 = blockIdx.y * 32;
    const float* xb = x + (long)b * DD * NN;
    ushort* xhb = xhi + (long)b * DD * NN;
#pragma unroll
    for (int r = 0; r < 4; ++r) {
      const int dl = ty + r * 8;
      const float v = xb[(long)(d0 + dl) * NN + n0 + tx];
      tile[dl][tx] = v;
      xhb[(long)(d0 + dl) * NN + n0 + tx] = f2b(v);
    }
    __syncthreads();
#pragma unroll
    for (int r = 0; r < 4; ++r) {
      const int nl = ty + r * 8;
      const float v = tile[tx][nl];
      const ushort h = f2b(v);
      const long o = (long)b * NN * DD + (long)(n0 + nl) * DD + d0 + tx;
      xTh[o] = h;
      xTl[o] = f2b(v - b2f(h));
    }
  } else {
    const int w = (z - 4) * 2 + (blockIdx.x >> 5);
    const float* W = (w == 0) ? WQ : (w == 1) ? WK : (w == 2) ? WV : WO;
    ushort* Th = (w == 0) ? qh : (w == 1) ? kh : (w == 2) ? vh : oh;
    ushort* Tl = (w == 0) ? ql : (w == 1) ? kl_ : nullptr;
    const int k0 = (blockIdx.x & 31) * 32, d0 = blockIdx.y * 32;
#pragma unroll
    for (int r = 0; r < 4; ++r) {
      const int kl = ty + r * 8;
      tile[kl][tx] = W[(long)(k0 + kl) * DD + d0 + tx];
    }
    __syncthreads();
#pragma unroll
    for (int r = 0; r < 4; ++r) {
      const int dl = ty + r * 8;
      const float v = tile[tx][dl];              // = W[k0+tx][d0+dl]
      const ushort h = f2b(v);
      const long o = (long)(d0 + dl) * KK + k0 + tx;
      Th[o] = h;
      if (Tl) Tl[o] = f2b(v - b2f(h));
    }
  }
}

// ---------------------------------------------------------------------------
// Merged weight-product GEMM, 64x64 tiles, BK=32, 512 blocks:
//   id<256 : Mqk[m,n] = sum_k wqT[m,k] wkT[n,k]  (split 3-MFMA, split store)
//   id>=256: Mov[m,n] = sum_k woT[m,k] wvT[n,k]  (plain bf16)
// ---------------------------------------------------------------------------
__global__ __launch_bounds__(256) void gemm_w(
    const ushort* __restrict__ qh, const ushort* __restrict__ ql,
    const ushort* __restrict__ kh, const ushort* __restrict__ kl_,
    const ushort* __restrict__ vh, const ushort* __restrict__ oh,
    ushort* __restrict__ mqk_h, ushort* __restrict__ mqk_l,
    ushort* __restrict__ mov_h) {
  extern __shared__ ushort smem[];
  ushort* sAh = smem;            // [64][32] 4KB
  ushort* sAl = smem + 2048;
  ushort* sBh = smem + 4096;
  ushort* sBl = smem + 6144;

  const int id = blockIdx.x;
  const int half = id >> 8;                  // 0 = Mqk (split), 1 = Mov (plain)
  const int t = id & 255;
  const int m0 = (t >> 4) * 64, n0 = (t & 15) * 64;
  const ushort* A_h = half ? oh : qh;
  const ushort* B_h = half ? vh : kh;

  const int tid = threadIdx.x;
  const int lane = tid & 63, wave = tid >> 6;
  const int wm = (wave & 1) * 32, wn = (wave >> 1) * 32;
  const int r16 = lane & 15, quad = lane >> 4;
  const int kc = ((lane & 3) ^ ((lane >> 3) & 3)) * 8;   // swizzled k-chunk
  const int srow = lane >> 2;

  f32x4 acc[2][2];
#pragma unroll
  for (int i = 0; i < 2; ++i)
#pragma unroll
    for (int j = 0; j < 2; ++j) acc[i][j] = (f32x4){0.f, 0.f, 0.f, 0.f};

  for (int k0 = 0; k0 < KK; k0 += 32) {
    __syncthreads();
    {
      const int row = wave * 16 + srow;
      const long aoff = (long)(m0 + row) * KK + k0 + kc;
      const long boff = (long)(n0 + row) * KK + k0 + kc;
      async16(A_h + aoff, sAh + wave * 512);
      async16(B_h + boff, sBh + wave * 512);
      if (half == 0) {
        async16(ql + aoff, sAl + wave * 512);
        async16(kl_ + boff, sBl + wave * 512);
      }
    }
    __syncthreads();

    const int sw = (r16 >> 1) & 3;
    bfrag ah[2], bh[2], al[2], bl[2];
#pragma unroll
    for (int t2 = 0; t2 < 2; ++t2) {
      ah[t2] = *(const bfrag*)&sAh[(wm + t2 * 16 + r16) * 32 + (quad ^ sw) * 8];
      bh[t2] = *(const bfrag*)&sBh[(wn + t2 * 16 + r16) * 32 + (quad ^ sw) * 8];
      if (half == 0) {
        al[t2] = *(const bfrag*)&sAl[(wm + t2 * 16 + r16) * 32 + (quad ^ sw) * 8];
        bl[t2] = *(const bfrag*)&sBl[(wn + t2 * 16 + r16) * 32 + (quad ^ sw) * 8];
      }
    }
#pragma unroll
    for (int mt = 0; mt < 2; ++mt)
#pragma unroll
      for (int nt = 0; nt < 2; ++nt) {
        acc[mt][nt] = __builtin_amdgcn_mfma_f32_16x16x32_bf16(ah[mt], bh[nt], acc[mt][nt], 0, 0, 0);
        if (half == 0) {
          acc[mt][nt] = __builtin_amdgcn_mfma_f32_16x16x32_bf16(ah[mt], bl[nt], acc[mt][nt], 0, 0, 0);
          acc[mt][nt] = __builtin_amdgcn_mfma_f32_16x16x32_bf16(al[mt], bh[nt], acc[mt][nt], 0, 0, 0);
        }
      }
  }

#pragma unroll
  for (int mt = 0; mt < 2; ++mt)
#pragma unroll
    for (int nt = 0; nt < 2; ++nt)
#pragma unroll
      for (int reg = 0; reg < 4; ++reg) {
        const int ml = wm + mt * 16 + quad * 4 + reg;
        const int nl = wn + nt * 16 + r16;
        const float v = acc[mt][nt][reg];
        const long o = (long)(m0 + ml) * DD + n0 + nl;
        if (half == 0) {
          const ushort h = f2b(v);
          mqk_h[o] = h;
          mqk_l[o] = f2b(v - b2f(h));
        } else {
          mov_h[o] = f2b(v);
        }
      }
}

// ---------------------------------------------------------------------------
// bf16 MFMA GEMM, 128x128 block tile, 4 waves (2x2) of 64x64, 16x16x32 MFMA.
// T3-minimal recipe form (m248v2: +10% over naive 2-phase), double-buffered:
//   LDS = 2 buffers x 32KB = 64KB -> 2 blocks/CU (the R0 occupancy that
//   cross-block-overlaps; R2/R3's 1-block/CU configs regressed).
//   Per K-tile t (cur = t&1), ONE barrier:
//     STAGE(t+1 -> buf[cur^1])   ; issued BEFORE compute
//     16 ds_reads of buf[cur]    ; compiler-counted lgkmcnt
//     setprio(1); MFMA cluster; setprio(0)
//     sched_barrier(0); s_waitcnt vmcnt(0)   ; t+1 loads aged a full cluster
//     s_barrier; sched_barrier(0)            ; buf[cur^1] resident block-wide
//   Overwrite safety: STAGE(cur^1) comes after the barrier that ends tile
//   t-1; every wave's t-1 reads of buf[cur^1] were register-consumed by its
//   MFMAs before that barrier.
// SPLIT=1: BK=32, hi|lo packed per 128B row (chunks 0-3 = hi k, 4-7 = lo),
//   proven ^(row&7) chunk swizzle (R2/R3: 0 conflicts), 48 MFMA/tile (hh,
//   hl, lh). Staging pre-swizzles the per-lane GLOBAL source (LDS dest
//   linear, m104/m173).
// SPLIT=0: BK=64, rows = 8 k-chunks, same ^(row&7) swizzle (R0: 0 conflicts),
//   32 MFMA/tile.
// Fragment layouts (HW-verified, learn_hip m89):
//   A[m=lane&15][k=quad*8+j], B[n=lane&15][k=quad*8+j],
//   C/D: col=lane&15, row=quad*4+reg.
// TRIA : A staged from triangular tile layout; K limited to m0+128.
// SWIZ : XCD-locality block mapping (assumes xcd = blockIdx.x % 8):
//   1: 512 blocks, (b, m0)=P, n0: M=16 tiles, N=8 tiles
//   2: 544 blocks (logits tri), g=(blk&7)*68+(blk>>3); b=g/136, t=g%136
//   3: 512 blocks, causal-balanced: XCD x owns mtiles {x, 15-x}
//   4: 512 blocks, swapped roles (M=8 d-tiles, N=16 i-tiles)
// STORE 0: split bf16 (C0=hi, C1=lo); 1: tri fp32; 2: bf16; 3: fp32 + Res.
// ---------------------------------------------------------------------------
template <int SPLIT, int TRIA, int STORE, int SWIZ>
__global__ __launch_bounds__(256) void gemm_mfma(
    const ushort* __restrict__ Ah, const ushort* __restrict__ Al,
    const ushort* __restrict__ Bh, const ushort* __restrict__ Bl,
    void* __restrict__ C0, void* __restrict__ C1, const float* __restrict__ Res,
    int K, int lda, int ldb, int ldc,
    long bA, long bB, long bC, long bR) {
  extern __shared__ ushort smem[];   // 2 x 16384 ushorts (sA 8192 | sB 8192)

  int b, m0, n0, tiC = 0;
  if (SWIZ == 2) {
    const int g = (blockIdx.x & 7) * 68 + (blockIdx.x >> 3);
    b = g / NTRI;
    int t = g - b * NTRI;
    int ti = 0;
    while ((ti + 1) * (ti + 2) / 2 <= t) ++ti;
    const int tj = t - ti * (ti + 1) / 2;
    m0 = ti * 128; n0 = tj * 128; tiC = t;
  } else if (SWIZ == 1) {
    const int g = (blockIdx.x & 7) * 64 + (blockIdx.x >> 3);
    const int P = g >> 3;
    b = P >> 4;
    m0 = (P & 15) * 128;
    n0 = (g & 7) * 128;
  } else if (SWIZ == 3) {
    const int xcd = blockIdx.x & 7;
    const int idx = blockIdx.x >> 3;      // [0,64)
    const int q = idx >> 3;               // [0,8)
    b = q >> 1;
    const int mt_ = (q & 1) ? (15 - xcd) : xcd;
    m0 = mt_ * 128;
    n0 = (idx & 7) * 128;
  } else {  // SWIZ == 4
    const int g = (blockIdx.x & 7) * 64 + (blockIdx.x >> 3);
    const int P = g >> 3;
    b = P >> 4;
    n0 = (P & 15) * 128;
    m0 = (g & 7) * 128;
  }
  const int kmax = TRIA ? (m0 + 128) : K;
  int triA0 = 0;
  if (TRIA) { const int ti = m0 >> 7; triA0 = ti * (ti + 1) / 2; }

  const ushort* A_h = Ah + (long)b * bA;
  const ushort* B_h = Bh + (long)b * bB;
  const ushort* A_l = SPLIT ? Al + (long)b * bA : nullptr;
  const ushort* B_l = SPLIT ? Bl + (long)b * bB : nullptr;

  const int tid = threadIdx.x;
  const int lane = tid & 63, wave = tid >> 6;
  const int wm = (wave & 1) * 64, wn = (wave >> 1) * 64;
  const int r16 = lane & 15, quad = lane >> 4;
  const int rk = r16 & 7;

  // staging lane mapping: 8 rows x 8 phys chunks per async16 (1KB)
  const int lrow = lane >> 3;                  // row within 8-row segment
  const int lc = (lane & 7) ^ lrow;            // logical chunk = phys ^ row&7
  // SPLIT: logical chunks 0-3 = hi k-chunks, 4-7 = lo k-chunks
  const int lckS = (lc & 3) * 8;
  const bool lo_src = lc >= 4;
  // plain: logical chunk = k-chunk of BK=64
  const int kcP = lc * 8;

  f32x4 acc[4][4];
#pragma unroll
  for (int i = 0; i < 4; ++i)
#pragma unroll
    for (int j = 0; j < 4; ++j) acc[i][j] = (f32x4){0.f, 0.f, 0.f, 0.f};

  auto STAGE = [&](int db, int t) {
    ushort* dst = smem + db * 16384;
    if (SPLIT) {
      const int k0 = t << 5;
#pragma unroll
      for (int s = 0; s < 4; ++s) {
        const int seg = wave * 4 + s;          // [0,16): 8-row group
        const int row = seg * 8 + lrow;        // [0,128)
        const ushort* baseA = lo_src ? A_l : A_h;
        const ushort* baseB = lo_src ? B_l : B_h;
        async16(baseA + (long)(m0 + row) * lda + k0 + lckS, dst + seg * 512);
        async16(baseB + (long)(n0 + row) * ldb + k0 + lckS, dst + 8192 + seg * 512);
      }
    } else {
      const int k0 = t << 6;
#pragma unroll
      for (int s = 0; s < 4; ++s) {
        const int seg = wave * 4 + s;
        const int row = seg * 8 + lrow;
        long aoff;
        if (TRIA)
          aoff = (long)(triA0 + (k0 >> 7)) * TRI_ELEMS + (long)row * 128 + (k0 & 127) + kcP;
        else
          aoff = (long)(m0 + row) * lda + k0 + kcP;
        async16(A_h + aoff, dst + seg * 512);
        async16(B_h + (long)(n0 + row) * ldb + k0 + kcP, dst + 8192 + seg * 512);
      }
    }
  };

  const int T = kmax >> (SPLIT ? 5 : 6);
  STAGE(0, 0);
  asm volatile("s_waitcnt vmcnt(0)" ::: "memory");
  __builtin_amdgcn_s_barrier();
  __builtin_amdgcn_sched_barrier(0);

  for (int t = 0; t < T; ++t) {
    const int cur = t & 1;
    if (t + 1 < T) STAGE(cur ^ 1, t + 1);      // issue BEFORE compute
    const ushort* sA = smem + cur * 16384;
    const ushort* sB = sA + 8192;

    if (SPLIT) {
      bfrag ah[4], al[4], bh[4], bl[4];
#pragma unroll
      for (int f = 0; f < 4; ++f) {
        const int arow = (wm + f * 16 + r16) * 64;
        const int brow = (wn + f * 16 + r16) * 64;
        ah[f] = *(const bfrag*)&sA[arow + (quad ^ rk) * 8];
        al[f] = *(const bfrag*)&sA[arow + ((quad + 4) ^ rk) * 8];
        bh[f] = *(const bfrag*)&sB[brow + (quad ^ rk) * 8];
        bl[f] = *(const bfrag*)&sB[brow + ((quad + 4) ^ rk) * 8];
      }
      __builtin_amdgcn_s_setprio(1);
#pragma unroll
      for (int mt = 0; mt < 4; ++mt)
#pragma unroll
        for (int nt = 0; nt < 4; ++nt) {
          acc[mt][nt] = __builtin_amdgcn_mfma_f32_16x16x32_bf16(ah[mt], bh[nt], acc[mt][nt], 0, 0, 0);
          acc[mt][nt] = __builtin_amdgcn_mfma_f32_16x16x32_bf16(ah[mt], bl[nt], acc[mt][nt], 0, 0, 0);
          acc[mt][nt] = __builtin_amdgcn_mfma_f32_16x16x32_bf16(al[mt], bh[nt], acc[mt][nt], 0, 0, 0);
        }
      __builtin_amdgcn_s_setprio(0);
    } else {
#pragma unroll
      for (int ksub = 0; ksub < 2; ++ksub) {
        const int ch = ((ksub * 4 + quad) ^ rk) * 8;     // physical chunk
        bfrag a4[4], b4[4];
#pragma unroll
        for (int f = 0; f < 4; ++f) {
          a4[f] = *(const bfrag*)&sA[(wm + f * 16 + r16) * 64 + ch];
          b4[f] = *(const bfrag*)&sB[(wn + f * 16 + r16) * 64 + ch];
        }
        __builtin_amdgcn_s_setprio(1);
#pragma unroll
        for (int mt = 0; mt < 4; ++mt)
#pragma unroll
          for (int nt = 0; nt < 4; ++nt)
            acc[mt][nt] = __builtin_amdgcn_mfma_f32_16x16x32_bf16(a4[mt], b4[nt], acc[mt][nt], 0, 0, 0);
        __builtin_amdgcn_s_setprio(0);
      }
    }

    __builtin_amdgcn_sched_barrier(0);
    asm volatile("s_waitcnt vmcnt(0)" ::: "memory");   // t+1 loads landed
    __builtin_amdgcn_s_barrier();                      // buf[cur^1] ready
    __builtin_amdgcn_sched_barrier(0);
  }

  // epilogue
#pragma unroll
  for (int mt = 0; mt < 4; ++mt)
#pragma unroll
    for (int nt = 0; nt < 4; ++nt)
#pragma unroll
      for (int reg = 0; reg < 4; ++reg) {
        const int ml = wm + mt * 16 + quad * 4 + reg;
        const int nl = wn + nt * 16 + r16;
        const float v = acc[mt][nt][reg];
        if (STORE == 0) {
          ushort* Ch = (ushort*)C0 + (long)b * bC;
          ushort* Cl = (ushort*)C1 + (long)b * bC;
          const long o = (long)(m0 + ml) * ldc + n0 + nl;
          const ushort h = f2b(v);
          Ch[o] = h;
          Cl[o] = f2b(v - b2f(h));
        } else if (STORE == 1) {
          float* C = (float*)C0 + (long)b * bC + (long)tiC * TRI_ELEMS;
          C[ml * 128 + nl] = v;
        } else if (STORE == 2) {
          ushort* C = (ushort*)C0 + (long)b * bC;
          C[(long)(m0 + ml) * ldc + n0 + nl] = f2b(v);
        } else {
          float* C = (float*)C0 + (long)b * bC;
          const float* R = Res + (long)b * bR;
          const long o = (long)(m0 + ml) * ldc + n0 + nl;
          C[o] = R[o] + v;
        }
      }
}

// ---------------------------------------------------------------------------
// Causal softmax over triangular-tiled logits. One block per row (b, i).
// Writes bf16 A in tri layout, zero-filling diagonal-tile cols beyond i.
// ---------------------------------------------------------------------------
__global__ __launch_bounds__(256) void softmax_tri(
    const float* __restrict__ L, ushort* __restrict__ Aout) {
  const int row = blockIdx.x;
  const int b = row >> 11, i = row & (NN - 1);
  const int ti = i >> 7, ml = i & 127;
  const long base = (long)b * ((long)NTRI * TRI_ELEMS);
  const int trib = ti * (ti + 1) / 2;
  const int len = i + 1;
  const int tot = (ti + 1) * 128;
  const int tid = threadIdx.x;
  __shared__ float red[256];
  float vv[8];
  float m = -INFINITY;
#pragma unroll
  for (int u = 0; u < 8; ++u) {
    const int j = tid + u * 256;
    if (j < len) {
      const float v = L[base + (long)(trib + (j >> 7)) * TRI_ELEMS + ml * 128 + (j & 127)];
      vv[u] = v;
      m = fmaxf(m, v);
    }
  }
  red[tid] = m; __syncthreads();
  for (int s = 128; s; s >>= 1) { if (tid < s) red[tid] = fmaxf(red[tid], red[tid + s]); __syncthreads(); }
  m = red[0]; __syncthreads();
  float sum = 0.f;
#pragma unroll
  for (int u = 0; u < 8; ++u) {
    const int j = tid + u * 256;
    if (j < len) { const float e = __expf(vv[u] - m); vv[u] = e; sum += e; }
  }
  red[tid] = sum; __syncthreads();
  for (int s = 128; s; s >>= 1) { if (tid < s) red[tid] += red[tid + s]; __syncthreads(); }
  const float inv = 1.f / red[0];
#pragma unroll
  for (int u = 0; u < 8; ++u) {
    const int j = tid + u * 256;
    if (j < tot) {
      const ushort o = (j < len) ? f2b(vv[u] * inv) : (ushort)0;
      Aout[base + (long)(trib + (j >> 7)) * TRI_ELEMS + ml * 128 + (j & 127)] = o;
    }
  }
}

// ---------------------------------------------------------------------------
// Pipeline (all MFMA operands k-contiguous by construction):
//  0. prep: x -> x_hi, xT hi/lo; W_Q..W_O -> WT [d][k] bf16     (1 dispatch)
//  1. gemm_w: Mqk (split) + Mov (plain) in one 512-block dispatch
//  2. tT[i,d] = sum_e xT[i,e] Mqk[d,e]      split, SWIZ=1, 512 blocks
//  3. logits[i,j] = sum_d xT[i,d] tT[j,d]   split, tri tiles, SWIZ=2, 544
//  4. A = causal softmax (bf16, tri layout, zero-padded diag tiles)
//  5. ctxT[i,e] = sum_{t<=i} A[i,t] x[e,t]  plain, causal K, SWIZ=3 (bal)
//  6. out[d,i] = x[d,i] + sum_e Mov[d,e] ctxT[i,e]   plain + res, SWIZ=4
// ---------------------------------------------------------------------------
extern "C" void kernel_launch(void* const* d_in, const int* in_sizes, int n_in,
                              void* d_out, int out_size, void* d_ws, size_t ws_size,
                              hipStream_t stream) {
  const float* x = (const float*)d_in[0];
  const float* WQ = (const float*)d_in[1];
  const float* WK = (const float*)d_in[2];
  const float* WV = (const float*)d_in[3];
  const float* WO = (const float*)d_in[4];
  float* out = (float*)d_out;

  const long XE = (long)BB * DD * NN;    // 8M elements
  const long WE = (long)DD * KK;         // 1M elements
  ushort* x_hi = (ushort*)d_ws;
  ushort* xTh = x_hi + XE;
  ushort* xTl = xTh + XE;
  ushort* wqT_h = xTl + XE;
  ushort* wqT_l = wqT_h + WE;
  ushort* wkT_h = wqT_l + WE;
  ushort* wkT_l = wkT_h + WE;
  ushort* wvT_h = wkT_l + WE;
  ushort* woT_h = wvT_h + WE;
  ushort* mqk_h = woT_h + WE;
  ushort* mqk_l = mqk_h + WE;
  ushort* mov_h = mqk_l + WE;
  ushort* tTh = mov_h + WE;
  ushort* tTl = tTh + XE;
  float* logits = (float*)(tTl + XE);    // B*NTRI*TRI_ELEMS fp32 (~35.7MB)
  ushort* A_tri = tTh;                   // overlays tT hi+lo (dead after step 3)
  ushort* ctxT = (ushort*)logits;        // overlays logits (dead after softmax)
  const long TRIB = (long)NTRI * TRI_ELEMS;
  const long XB = XE / BB;

  prep<<<dim3(64, 32, 6), dim3(32, 8), 0, stream>>>(
      x, WQ, WK, WV, WO, x_hi, xTh, xTl,
      wqT_h, wqT_l, wkT_h, wkT_l, wvT_h, woT_h);

  // Mqk (split) + Mov (plain), merged 64-tile dispatch
  gemm_w<<<dim3(512), 256, 16384, stream>>>(
      wqT_h, wqT_l, wkT_h, wkT_l, wvT_h, woT_h, mqk_h, mqk_l, mov_h);

  // tT = xT * Mqk^T (split, recipe-form dbuf BK=32, 64KB LDS, 2 blk/CU)
  gemm_mfma<1, 0, 0, 1><<<dim3(512), 256, 65536, stream>>>(
      xTh, xTl, mqk_h, mqk_l, tTh, tTl, nullptr,
      DD, DD, DD, DD, XB, 0, XB, 0);

  // logits (lower tri tiles, split recipe-form dbuf)
  gemm_mfma<1, 0, 1, 2><<<dim3(BB * NTRI), 256, 65536, stream>>>(
      xTh, xTl, tTh, tTl, logits, nullptr, nullptr,
      DD, DD, DD, 0, XB, XB, TRIB, 0);

  softmax_tri<<<dim3(BB * NN), 256, 0, stream>>>(logits, A_tri);

  // ctxT = A * x^T (tri A, causal K-limit, balanced XCD swizzle, dbuf)
  gemm_mfma<0, 1, 2, 3><<<dim3(512), 256, 65536, stream>>>(
      A_tri, nullptr, x_hi, nullptr, ctxT, nullptr, nullptr,
      NN, 0, NN, DD, TRIB, XB, XB, 0);

  // out = x + Mov * ctx (SWIZ=4: M=8 d-tiles, N=16 i-tiles, dbuf)
  gemm_mfma<0, 0, 3, 4><<<dim3(512), 256, 65536, stream>>>(
      mov_h, nullptr, ctxT, nullptr, out, nullptr, x,
      DD, DD, DD, NN, 0, XB, XB, XB);
}